// Round 14
// baseline (546.477 us; speedup 1.0000x reference)
//
#include <hip/hip_runtime.h>
#include <hip/hip_fp16.h>

#define N_NODES 50000
#define N_EDGES 800000
#define EL (N_EDGES + N_NODES) /* 850000 */
#define F_IN 767
#define HID 256
#define NHEAD 8
#define KSTEPS 24 /* ceil(767/32) */
#define NCH 12    /* 64-k chunks */
#define NB_SCAN 49 /* ceil(50000/1024) */

typedef __attribute__((ext_vector_type(8))) short short8;
typedef __attribute__((ext_vector_type(4))) float f32x4;

struct H4 { __half2 a, b; };  // 8-byte gather unit

static __device__ __forceinline__ unsigned short f2bf(float f) {
  unsigned int u = __float_as_uint(f);
  unsigned int r = (u + 0x7fffu + ((u >> 16) & 1u)) >> 16;
  return (unsigned short)r;
}
static __device__ __forceinline__ float bf2f(unsigned short h) {
  return __uint_as_float(((unsigned int)h) << 16);
}

// ---- prep: split W into bf16 hi/lo and repack into MFMA fragment order ----
__global__ __launch_bounds__(256) void prep_kernel(
    const float* __restrict__ W, short* __restrict__ Wh, short* __restrict__ Wl) {
  int idx = blockIdx.x * 256 + threadIdx.x;  // 768*256 threads
  int k = idx >> 8, n = idx & 255;
  float v = (k < F_IN) ? W[k * HID + n] : 0.f;
  unsigned short h = f2bf(v);
  float lf = v - bf2f(h);
  unsigned short lo = f2bf(lf);
  int ks = k >> 5, oct = (k >> 3) & 3, j = k & 7;
  int nf = n >> 4;
  int l = (n & 15) | (oct << 4);
  int addr = ((ks * 16 + nf) * 64 + l) * 8 + j;
  Wh[addr] = (short)h;
  Wl[addr] = (short)lo;
}

// ---- GEMM1 (R12 champion + 4-waves/EU residency): A in bf16 single plane,
//      B split hi/lo (2-pass MFMA), BK=64 dbuf LDS (16KB), XOR-swizzle,
//      depth-2 chunk prefetch, B prefetch 1 ks ahead, fused as1/ad1 epilogue.
//      VGPR 120 <= 128 cap for 4 waves/SIMD -> 4 blocks/CU, no spill.
__global__ __launch_bounds__(256, 4) void gemm1_mfma_kernel(
    const float* __restrict__ x, const short* __restrict__ Wh,
    const short* __restrict__ Wl, __half* __restrict__ h1h,
    const float* __restrict__ att_s, const float* __restrict__ att_d,
    float* __restrict__ as1, float* __restrict__ ad1) {
  __shared__ __align__(16) short Ah[2][2][2048];
  const int tid = threadIdx.x;
  const int lane = tid & 63, wav = tid >> 6;
  const int m0 = blockIdx.x * 64;
  const int m_local = tid >> 2, oct = tid & 3;
  const int gm = m0 + m_local;
  const bool vrow = (gm < N_NODES);
  const long xbase = (long)gm * F_IN;
  const int wu0 = ((m_local >> 4) * 64) + ((m_local & 15) | (oct << 4));
  const int wu = wu0 ^ ((((unsigned)wu0 >> 4) & 3) << 1);

  float atts[4], attd[4];
#pragma unroll
  for (int nf = 0; nf < 4; ++nf) {
    int c = wav * 64 + nf * 16 + (lane & 15);
    atts[nf] = att_s[c];
    attd[nf] = att_d[c];
  }

  f32x4 acc[4][4];
#pragma unroll
  for (int i = 0; i < 4; ++i)
#pragma unroll
    for (int j = 0; j < 4; ++j) acc[i][j] = (f32x4){0.f, 0.f, 0.f, 0.f};

  // depth-2 chunk prefetch (16 floats each: 2 k-steps)
  float xc[16], xn[16];
  {
    int kb = oct * 8;
    if (vrow) {
#pragma unroll
      for (int ki = 0; ki < 2; ++ki)
#pragma unroll
        for (int j = 0; j < 8; ++j) {
          xc[ki * 8 + j] = x[xbase + kb + ki * 32 + j];
          xn[ki * 8 + j] = x[xbase + 64 + kb + ki * 32 + j];
        }
    } else {
#pragma unroll
      for (int j = 0; j < 16; ++j) { xc[j] = 0.f; xn[j] = 0.f; }
    }
  }
  // B prefetch for ks=0
  short8 bhc[4], blc[4];
  {
    const short* wb = Wh + ((wav * 4) * 64 + lane) * 8;
    const short* wbl = Wl + ((wav * 4) * 64 + lane) * 8;
#pragma unroll
    for (int nf = 0; nf < 4; ++nf) {
      bhc[nf] = *(const short8*)(wb + nf * 512);
      blc[nf] = *(const short8*)(wbl + nf * 512);
    }
  }

#pragma unroll 2
  for (int c = 0; c < NCH; ++c) {
    // convert both k-steps of chunk c -> LDS buf[c&1] (bf16 hi only)
#pragma unroll
    for (int ki = 0; ki < 2; ++ki) {
      short8 hi8;
#pragma unroll
      for (int j = 0; j < 8; ++j) hi8[j] = (short)f2bf(xc[ki * 8 + j]);
      *(short8*)&Ah[c & 1][ki][wu * 8] = hi8;
    }
    // rotate prefetch; issue x loads for chunk c+2
    {
#pragma unroll
      for (int j = 0; j < 16; ++j) xc[j] = xn[j];
      int s = c + 2;
      if (s < NCH - 1) {
        int kb = s * 64 + oct * 8;
        if (vrow) {
#pragma unroll
          for (int ki = 0; ki < 2; ++ki)
#pragma unroll
            for (int j = 0; j < 8; ++j) xn[ki * 8 + j] = x[xbase + kb + ki * 32 + j];
        } else {
#pragma unroll
          for (int j = 0; j < 16; ++j) xn[j] = 0.f;
        }
      } else if (s == NCH - 1) {
        int kb = s * 64 + oct * 8;
#pragma unroll
        for (int ki = 0; ki < 2; ++ki)
#pragma unroll
          for (int j = 0; j < 8; ++j) {
            int k = kb + ki * 32 + j;
            xn[ki * 8 + j] = (vrow && k < F_IN) ? x[xbase + k] : 0.f;
          }
      }
    }
    __syncthreads();
#pragma unroll
    for (int ki = 0; ki < 2; ++ki) {
      const int ksg = c * 2 + ki;
      short8 ah[4];
#pragma unroll
      for (int mf = 0; mf < 4; ++mf) {
        int u = mf * 64 + lane;
        int us = u ^ ((((unsigned)u >> 4) & 3) << 1);
        ah[mf] = *(short8*)&Ah[c & 1][ki][us * 8];
      }
      // B prefetch for ksg+1 (in flight across the MFMA block)
      short8 bhn[4], bln[4];
      if (ksg + 1 < KSTEPS) {
        const short* wb = Wh + (((ksg + 1) * 16 + wav * 4) * 64 + lane) * 8;
        const short* wbl = Wl + (((ksg + 1) * 16 + wav * 4) * 64 + lane) * 8;
#pragma unroll
        for (int nf = 0; nf < 4; ++nf) {
          bhn[nf] = *(const short8*)(wb + nf * 512);
          bln[nf] = *(const short8*)(wbl + nf * 512);
        }
      }
      // 2 passes of 16 independent MFMAs (A-hi x B-hi, A-hi x B-lo)
#pragma unroll
      for (int mf = 0; mf < 4; ++mf)
#pragma unroll
        for (int nf = 0; nf < 4; ++nf)
          acc[mf][nf] = __builtin_amdgcn_mfma_f32_16x16x32_bf16(ah[mf], bhc[nf], acc[mf][nf], 0, 0, 0);
#pragma unroll
      for (int mf = 0; mf < 4; ++mf)
#pragma unroll
        for (int nf = 0; nf < 4; ++nf)
          acc[mf][nf] = __builtin_amdgcn_mfma_f32_16x16x32_bf16(ah[mf], blc[nf], acc[mf][nf], 0, 0, 0);
#pragma unroll
      for (int nf = 0; nf < 4; ++nf) {
        bhc[nf] = bhn[nf];
        blc[nf] = bln[nf];
      }
    }
  }

  // epilogue: h1 (fp16) store + fused as1/ad1 reduction
  const int r0 = (lane >> 4) * 4, cn = lane & 15;
#pragma unroll
  for (int mf = 0; mf < 4; ++mf) {
    int rowb = m0 + mf * 16 + r0;
#pragma unroll
    for (int rr = 0; rr < 4; ++rr) {
      int row = rowb + rr;
      bool ok = (row < N_NODES);
      if (ok) {
#pragma unroll
        for (int nf = 0; nf < 4; ++nf)
          h1h[(long)row * HID + wav * 64 + nf * 16 + cn] =
              __float2half_rn(acc[mf][nf][rr]);
      }
      float s0 = acc[mf][0][rr] * atts[0] + acc[mf][1][rr] * atts[1];
      float s1 = acc[mf][2][rr] * atts[2] + acc[mf][3][rr] * atts[3];
      float d0 = acc[mf][0][rr] * attd[0] + acc[mf][1][rr] * attd[1];
      float d1 = acc[mf][2][rr] * attd[2] + acc[mf][3][rr] * attd[3];
#pragma unroll
      for (int o = 1; o < 16; o <<= 1) {
        s0 += __shfl_xor(s0, o, 64);
        s1 += __shfl_xor(s1, o, 64);
        d0 += __shfl_xor(d0, o, 64);
        d1 += __shfl_xor(d1, o, 64);
      }
      if (ok && cn == 0) {
        as1[row * NHEAD + wav * 2]     = s0;
        as1[row * NHEAD + wav * 2 + 1] = s1;
        ad1[row * NHEAD + wav * 2]     = d0;
        ad1[row * NHEAD + wav * 2 + 1] = d1;
      }
    }
  }
}

// ---------------- CSR build ----------------
__global__ void count_kernel(const int* __restrict__ ei, int* __restrict__ deg) {
  int e = blockIdx.x * blockDim.x + threadIdx.x;
  if (e >= EL) return;
  int dst = (e < N_EDGES) ? ei[N_EDGES + e] : (e - N_EDGES);
  atomicAdd(&deg[dst], 1);
}

__global__ __launch_bounds__(1024) void scan_part_kernel(
    const int* __restrict__ deg, int* __restrict__ off, int* __restrict__ btot) {
  __shared__ int warp_sums[16];
  const int tid = threadIdx.x;
  const int lane = tid & 63, wid = tid >> 6;
  int i = blockIdx.x * 1024 + tid;
  int v = (i < N_NODES) ? deg[i] : 0;
  int x = v;
#pragma unroll
  for (int o = 1; o < 64; o <<= 1) {
    int y = __shfl_up(x, o, 64);
    if (lane >= o) x += y;
  }
  if (lane == 63) warp_sums[wid] = x;
  __syncthreads();
  if (wid == 0) {
    int ws = (lane < 16) ? warp_sums[lane] : 0;
#pragma unroll
    for (int o = 1; o < 16; o <<= 1) {
      int y = __shfl_up(ws, o, 64);
      if (lane >= o) ws += y;
    }
    if (lane < 16) warp_sums[lane] = ws;
  }
  __syncthreads();
  int wprefix = (wid > 0) ? warp_sums[wid - 1] : 0;
  if (i < N_NODES) off[i] = wprefix + x - v;
  if (tid == 1023) btot[blockIdx.x] = warp_sums[15];
}

__global__ __launch_bounds__(64) void scan_tops_kernel(
    const int* __restrict__ btot, int* __restrict__ bo) {
  int lane = threadIdx.x;
  int v = (lane < NB_SCAN) ? btot[lane] : 0;
  int x = v;
#pragma unroll
  for (int o = 1; o < 64; o <<= 1) {
    int y = __shfl_up(x, o, 64);
    if (lane >= o) x += y;
  }
  if (lane < NB_SCAN) bo[lane] = x - v;  // exclusive
}

__global__ void scan_add_kernel(int* __restrict__ off, const int* __restrict__ bo) {
  int i = blockIdx.x * blockDim.x + threadIdx.x;
  if (i > N_NODES) return;
  if (i == N_NODES) off[i] = EL;
  else off[i] += bo[i >> 10];
}

// ---- fill CSR (pure; attention numerators computed inline in agg1) ----
__global__ void fill_kernel(const int* __restrict__ ei, const int* __restrict__ off,
                            int* __restrict__ cur, int* __restrict__ csr) {
  int e = blockIdx.x * blockDim.x + threadIdx.x;
  if (e >= EL) return;
  int src, dst;
  if (e < N_EDGES) { src = ei[e]; dst = ei[N_EDGES + e]; }
  else { src = e - N_EDGES; dst = src; }
  int pos = atomicAdd(&cur[dst], 1);
  csr[off[dst] + pos] = src;
}

// ---- layer-1 aggregation (inline no-max softmax) + FUSED layer-2 linear ----
// 4 nodes/block, 64 thr/node (one wave per node), 8B gathers, 4-unroll.
// Logits e = as+ad ~ N(0,~1.1): |e| < ~7 over 6.8M samples -> exp safe in fp32.
__global__ __launch_bounds__(256) void agg1_kernel(
    const __half* __restrict__ h1h, const float* __restrict__ as1,
    const float* __restrict__ ad1, const int* __restrict__ off,
    const int* __restrict__ csr, const float* __restrict__ b1,
    const float* __restrict__ W2, const float* __restrict__ att_s2,
    const float* __restrict__ att_d2, float* __restrict__ h2,
    float* __restrict__ as2, float* __restrict__ ad2) {
  __shared__ float W2s[HID * 11];  // stride-11 pad (bank spread)
  {
    int tid = threadIdx.x;
    for (int i = tid; i < HID * 10; i += 256)
      W2s[(i / 10) * 11 + (i % 10)] = W2[i];
  }
  __syncthreads();
  const int t = threadIdx.x & 63;
  const int n = blockIdx.x * 4 + (threadIdx.x >> 6);
  if (n >= N_NODES) return;
  const int head = t >> 3;  // 4 channels (t*4..t*4+3) all inside one head
  const float adn = ad1[n * NHEAD + head];
  const int j0 = off[n], j1 = off[n + 1];
  float a0 = 0.f, a1 = 0.f, a2 = 0.f, a3 = 0.f, den = 0.f;
  int j = j0;
  for (; j + 3 < j1; j += 4) {
    int s[4];
    float pw[4];
    H4 v[4];
#pragma unroll
    for (int q = 0; q < 4; ++q) s[q] = csr[j + q];
#pragma unroll
    for (int q = 0; q < 4; ++q) {
      float e = as1[s[q] * NHEAD + head] + adn;
      e = (e >= 0.f) ? e : 0.2f * e;
      pw[q] = __expf(e);
      v[q] = *(const H4*)&h1h[s[q] * HID + t * 4];
    }
#pragma unroll
    for (int q = 0; q < 4; ++q) {
      float2 fa = __half22float2(v[q].a), fb = __half22float2(v[q].b);
      den += pw[q];
      a0 += pw[q] * fa.x;
      a1 += pw[q] * fa.y;
      a2 += pw[q] * fb.x;
      a3 += pw[q] * fb.y;
    }
  }
  for (; j < j1; ++j) {
    int s0 = csr[j];
    float e = as1[s0 * NHEAD + head] + adn;
    e = (e >= 0.f) ? e : 0.2f * e;
    float p0 = __expf(e);
    H4 v0 = *(const H4*)&h1h[s0 * HID + t * 4];
    float2 fa = __half22float2(v0.a), fb = __half22float2(v0.b);
    den += p0;
    a0 += p0 * fa.x;
    a1 += p0 * fa.y;
    a2 += p0 * fb.x;
    a3 += p0 * fb.y;
  }
  float rden = 1.f / (den + 1e-16f);
  float4 bv = *(const float4*)&b1[t * 4];
  float vv[4];
  vv[0] = a0 * rden + bv.x;
  vv[1] = a1 * rden + bv.y;
  vv[2] = a2 * rden + bv.z;
  vv[3] = a3 * rden + bv.w;
#pragma unroll
  for (int c = 0; c < 4; ++c) vv[c] = (vv[c] > 0.f) ? vv[c] : (__expf(vv[c]) - 1.f);
  // fused layer-2 linear: h2[n][k] = sum_c o1[n][c]*W2[c][k], wave-reduced
  float hk[10];
#pragma unroll
  for (int k = 0; k < 10; ++k) {
    float pk = vv[0] * W2s[(t * 4 + 0) * 11 + k] +
               vv[1] * W2s[(t * 4 + 1) * 11 + k] +
               vv[2] * W2s[(t * 4 + 2) * 11 + k] +
               vv[3] * W2s[(t * 4 + 3) * 11 + k];
#pragma unroll
    for (int o = 32; o >= 1; o >>= 1) pk += __shfl_xor(pk, o, 64);
    hk[k] = pk;
  }
  if (t == 0) {
    float s = 0.f, d = 0.f;
#pragma unroll
    for (int k = 0; k < 10; ++k) {
      h2[n * 10 + k] = hk[k];
      s += hk[k] * att_s2[k];
      d += hk[k] * att_d2[k];
    }
    as2[n] = s;
    ad2[n] = d;
  }
}

// ---- layer-2 aggregation: 16-lane sub-groups, 16 nodes/block ----
__global__ __launch_bounds__(256) void agg2_kernel(
    const float* __restrict__ h2, const float* __restrict__ as2,
    const float* __restrict__ ad2, const int* __restrict__ off,
    const int* __restrict__ csr, const float* __restrict__ b2,
    float* __restrict__ out) {
  int g = threadIdx.x >> 4, l = threadIdx.x & 15;
  int n = blockIdx.x * 16 + g;
  if (n >= N_NODES) return;
  float adn = ad2[n];
  int j0 = off[n], j1 = off[n + 1];
  float acc = 0.f, den = 0.f;
  int j = j0;
  for (; j + 1 < j1; j += 2) {
    int s0 = csr[j], s1 = csr[j + 1];
    float e0 = as2[s0] + adn, e1 = as2[s1] + adn;
    e0 = (e0 >= 0.f) ? e0 : 0.2f * e0;
    e1 = (e1 >= 0.f) ? e1 : 0.2f * e1;
    float p0 = __expf(e0), p1v = __expf(e1);
    den += p0 + p1v;
    if (l < 10) acc += p0 * h2[s0 * 10 + l] + p1v * h2[s1 * 10 + l];
  }
  if (j < j1) {
    int s0 = csr[j];
    float e0 = as2[s0] + adn;
    e0 = (e0 >= 0.f) ? e0 : 0.2f * e0;
    float p0 = __expf(e0);
    den += p0;
    if (l < 10) acc += p0 * h2[s0 * 10 + l];
  }
  if (l < 10) out[n * 10 + l] = acc / (den + 1e-16f) + b2[l];
}

extern "C" void kernel_launch(void* const* d_in, const int* in_sizes, int n_in,
                              void* d_out, int out_size, void* d_ws, size_t ws_size,
                              hipStream_t stream) {
  const float* x    = (const float*)d_in[0];
  const int*   ei   = (const int*)d_in[1];
  const float* W1   = (const float*)d_in[2];
  const float* as1w = (const float*)d_in[3];
  const float* ad1w = (const float*)d_in[4];
  const float* b1   = (const float*)d_in[5];
  const float* W2   = (const float*)d_in[6];
  const float* as2w = (const float*)d_in[7];
  const float* ad2w = (const float*)d_in[8];
  const float* b2   = (const float*)d_in[9];
  float* out = (float*)d_out;

  char* p = (char*)d_ws;
  __half* h1h = (__half*)p; p += (size_t)N_NODES * HID * 2;
  float* a_s1 = (float*)p; p += (size_t)N_NODES * NHEAD * 4;
  float* a_d1 = (float*)p; p += (size_t)N_NODES * NHEAD * 4;
  float* h2   = (float*)p; p += (size_t)N_NODES * 10 * 4;
  float* a_s2 = (float*)p; p += (size_t)N_NODES * 4;
  float* a_d2 = (float*)p; p += (size_t)N_NODES * 4;
  short* Wh   = (short*)p; p += (size_t)KSTEPS * 16 * 64 * 8 * 2;
  short* Wl   = (short*)p; p += (size_t)KSTEPS * 16 * 64 * 8 * 2;
  int* deg    = (int*)p;   p += (size_t)N_NODES * 4;
  int* cur    = (int*)p;   p += (size_t)N_NODES * 4;
  int* off    = (int*)p;   p += (size_t)(N_NODES + 1) * 4;
  int* csr    = (int*)p;   p += (size_t)EL * 4;
  int* btot   = (int*)p;   p += 64 * 4;
  int* bo     = (int*)p;   p += 64 * 4;

  prep_kernel<<<768, 256, 0, stream>>>(W1, Wh, Wl);
  gemm1_mfma_kernel<<<(N_NODES + 63) / 64, 256, 0, stream>>>(
      x, Wh, Wl, h1h, as1w, ad1w, a_s1, a_d1);
  hipMemsetAsync(deg, 0, (size_t)N_NODES * 2 * 4, stream);  // deg + cur (adjacent)
  count_kernel<<<(EL + 255) / 256, 256, 0, stream>>>(ei, deg);
  scan_part_kernel<<<NB_SCAN, 1024, 0, stream>>>(deg, off, btot);
  scan_tops_kernel<<<1, 64, 0, stream>>>(btot, bo);
  scan_add_kernel<<<(N_NODES + 256) / 256, 256, 0, stream>>>(off, bo);
  fill_kernel<<<(EL + 255) / 256, 256, 0, stream>>>(ei, off, cur, csr);
  agg1_kernel<<<(N_NODES + 3) / 4, 256, 0, stream>>>(
      h1h, a_s1, a_d1, off, csr, b1, W2, as2w, ad2w, h2, a_s2, a_d2);
  agg2_kernel<<<(N_NODES + 15) / 16, 256, 0, stream>>>(h2, a_s2, a_d2, off, csr, b2, out);
}

// Round 15
// 479.347 us; speedup vs baseline: 1.1400x; 1.1400x over previous
//
#include <hip/hip_runtime.h>
#include <hip/hip_fp16.h>

#define N_NODES 50000
#define N_EDGES 800000
#define EL (N_EDGES + N_NODES) /* 850000 */
#define F_IN 767
#define HID 256
#define NHEAD 8
#define KSTEPS 24 /* ceil(767/32) */
#define NCH 12    /* 64-k chunks */
#define NB_SCAN 49 /* ceil(50000/1024) */

typedef __attribute__((ext_vector_type(8))) short short8;
typedef __attribute__((ext_vector_type(4))) float f32x4;

struct H4 { __half2 a, b; };  // 8-byte gather unit

static __device__ __forceinline__ unsigned short f2bf(float f) {
  unsigned int u = __float_as_uint(f);
  unsigned int r = (u + 0x7fffu + ((u >> 16) & 1u)) >> 16;
  return (unsigned short)r;
}
static __device__ __forceinline__ float bf2f(unsigned short h) {
  return __uint_as_float(((unsigned int)h) << 16);
}

// ---- prep: split W into bf16 hi/lo and repack into MFMA fragment order ----
__global__ __launch_bounds__(256) void prep_kernel(
    const float* __restrict__ W, short* __restrict__ Wh, short* __restrict__ Wl) {
  int idx = blockIdx.x * 256 + threadIdx.x;  // 768*256 threads
  int k = idx >> 8, n = idx & 255;
  float v = (k < F_IN) ? W[k * HID + n] : 0.f;
  unsigned short h = f2bf(v);
  float lf = v - bf2f(h);
  unsigned short lo = f2bf(lf);
  int ks = k >> 5, oct = (k >> 3) & 3, j = k & 7;
  int nf = n >> 4;
  int l = (n & 15) | (oct << 4);
  int addr = ((ks * 16 + nf) * 64 + l) * 8 + j;
  Wh[addr] = (short)h;
  Wl[addr] = (short)lo;
}

// ---- GEMM1 (R12 champion, 3 waves/EU): A in bf16 single plane,
//      B split hi/lo (2-pass MFMA), BK=64 dbuf LDS (16KB), XOR-swizzle,
//      depth-2 chunk prefetch, B prefetch 1 ks ahead, fused as1/ad1 epilogue.
//      VGPR need ~120 <= 168 cap for 3 waves/SIMD -> no spill (4-wave cap 128
//      forced 64-reg spill catastrophe in R14; 2-wave was the R12 baseline).
__global__ __launch_bounds__(256, 3) void gemm1_mfma_kernel(
    const float* __restrict__ x, const short* __restrict__ Wh,
    const short* __restrict__ Wl, __half* __restrict__ h1h,
    const float* __restrict__ att_s, const float* __restrict__ att_d,
    float* __restrict__ as1, float* __restrict__ ad1) {
  __shared__ __align__(16) short Ah[2][2][2048];
  const int tid = threadIdx.x;
  const int lane = tid & 63, wav = tid >> 6;
  const int m0 = blockIdx.x * 64;
  const int m_local = tid >> 2, oct = tid & 3;
  const int gm = m0 + m_local;
  const bool vrow = (gm < N_NODES);
  const long xbase = (long)gm * F_IN;
  const int wu0 = ((m_local >> 4) * 64) + ((m_local & 15) | (oct << 4));
  const int wu = wu0 ^ ((((unsigned)wu0 >> 4) & 3) << 1);

  float atts[4], attd[4];
#pragma unroll
  for (int nf = 0; nf < 4; ++nf) {
    int c = wav * 64 + nf * 16 + (lane & 15);
    atts[nf] = att_s[c];
    attd[nf] = att_d[c];
  }

  f32x4 acc[4][4];
#pragma unroll
  for (int i = 0; i < 4; ++i)
#pragma unroll
    for (int j = 0; j < 4; ++j) acc[i][j] = (f32x4){0.f, 0.f, 0.f, 0.f};

  // depth-2 chunk prefetch (16 floats each: 2 k-steps)
  float xc[16], xn[16];
  {
    int kb = oct * 8;
    if (vrow) {
#pragma unroll
      for (int ki = 0; ki < 2; ++ki)
#pragma unroll
        for (int j = 0; j < 8; ++j) {
          xc[ki * 8 + j] = x[xbase + kb + ki * 32 + j];
          xn[ki * 8 + j] = x[xbase + 64 + kb + ki * 32 + j];
        }
    } else {
#pragma unroll
      for (int j = 0; j < 16; ++j) { xc[j] = 0.f; xn[j] = 0.f; }
    }
  }
  // B prefetch for ks=0
  short8 bhc[4], blc[4];
  {
    const short* wb = Wh + ((wav * 4) * 64 + lane) * 8;
    const short* wbl = Wl + ((wav * 4) * 64 + lane) * 8;
#pragma unroll
    for (int nf = 0; nf < 4; ++nf) {
      bhc[nf] = *(const short8*)(wb + nf * 512);
      blc[nf] = *(const short8*)(wbl + nf * 512);
    }
  }

#pragma unroll 2
  for (int c = 0; c < NCH; ++c) {
    // convert both k-steps of chunk c -> LDS buf[c&1] (bf16 hi only)
#pragma unroll
    for (int ki = 0; ki < 2; ++ki) {
      short8 hi8;
#pragma unroll
      for (int j = 0; j < 8; ++j) hi8[j] = (short)f2bf(xc[ki * 8 + j]);
      *(short8*)&Ah[c & 1][ki][wu * 8] = hi8;
    }
    // rotate prefetch; issue x loads for chunk c+2
    {
#pragma unroll
      for (int j = 0; j < 16; ++j) xc[j] = xn[j];
      int s = c + 2;
      if (s < NCH - 1) {
        int kb = s * 64 + oct * 8;
        if (vrow) {
#pragma unroll
          for (int ki = 0; ki < 2; ++ki)
#pragma unroll
            for (int j = 0; j < 8; ++j) xn[ki * 8 + j] = x[xbase + kb + ki * 32 + j];
        } else {
#pragma unroll
          for (int j = 0; j < 16; ++j) xn[j] = 0.f;
        }
      } else if (s == NCH - 1) {
        int kb = s * 64 + oct * 8;
#pragma unroll
        for (int ki = 0; ki < 2; ++ki)
#pragma unroll
          for (int j = 0; j < 8; ++j) {
            int k = kb + ki * 32 + j;
            xn[ki * 8 + j] = (vrow && k < F_IN) ? x[xbase + k] : 0.f;
          }
      }
    }
    __syncthreads();
#pragma unroll
    for (int ki = 0; ki < 2; ++ki) {
      const int ksg = c * 2 + ki;
      short8 ah[4];
#pragma unroll
      for (int mf = 0; mf < 4; ++mf) {
        int u = mf * 64 + lane;
        int us = u ^ ((((unsigned)u >> 4) & 3) << 1);
        ah[mf] = *(short8*)&Ah[c & 1][ki][us * 8];
      }
      // B prefetch for ksg+1 (in flight across the MFMA block)
      short8 bhn[4], bln[4];
      if (ksg + 1 < KSTEPS) {
        const short* wb = Wh + (((ksg + 1) * 16 + wav * 4) * 64 + lane) * 8;
        const short* wbl = Wl + (((ksg + 1) * 16 + wav * 4) * 64 + lane) * 8;
#pragma unroll
        for (int nf = 0; nf < 4; ++nf) {
          bhn[nf] = *(const short8*)(wb + nf * 512);
          bln[nf] = *(const short8*)(wbl + nf * 512);
        }
      }
      // 2 passes of 16 independent MFMAs (A-hi x B-hi, A-hi x B-lo)
#pragma unroll
      for (int mf = 0; mf < 4; ++mf)
#pragma unroll
        for (int nf = 0; nf < 4; ++nf)
          acc[mf][nf] = __builtin_amdgcn_mfma_f32_16x16x32_bf16(ah[mf], bhc[nf], acc[mf][nf], 0, 0, 0);
#pragma unroll
      for (int mf = 0; mf < 4; ++mf)
#pragma unroll
        for (int nf = 0; nf < 4; ++nf)
          acc[mf][nf] = __builtin_amdgcn_mfma_f32_16x16x32_bf16(ah[mf], blc[nf], acc[mf][nf], 0, 0, 0);
#pragma unroll
      for (int nf = 0; nf < 4; ++nf) {
        bhc[nf] = bhn[nf];
        blc[nf] = bln[nf];
      }
    }
  }

  // epilogue: h1 (fp16) store + fused as1/ad1 reduction
  const int r0 = (lane >> 4) * 4, cn = lane & 15;
#pragma unroll
  for (int mf = 0; mf < 4; ++mf) {
    int rowb = m0 + mf * 16 + r0;
#pragma unroll
    for (int rr = 0; rr < 4; ++rr) {
      int row = rowb + rr;
      bool ok = (row < N_NODES);
      if (ok) {
#pragma unroll
        for (int nf = 0; nf < 4; ++nf)
          h1h[(long)row * HID + wav * 64 + nf * 16 + cn] =
              __float2half_rn(acc[mf][nf][rr]);
      }
      float s0 = acc[mf][0][rr] * atts[0] + acc[mf][1][rr] * atts[1];
      float s1 = acc[mf][2][rr] * atts[2] + acc[mf][3][rr] * atts[3];
      float d0 = acc[mf][0][rr] * attd[0] + acc[mf][1][rr] * attd[1];
      float d1 = acc[mf][2][rr] * attd[2] + acc[mf][3][rr] * attd[3];
#pragma unroll
      for (int o = 1; o < 16; o <<= 1) {
        s0 += __shfl_xor(s0, o, 64);
        s1 += __shfl_xor(s1, o, 64);
        d0 += __shfl_xor(d0, o, 64);
        d1 += __shfl_xor(d1, o, 64);
      }
      if (ok && cn == 0) {
        as1[row * NHEAD + wav * 2]     = s0;
        as1[row * NHEAD + wav * 2 + 1] = s1;
        ad1[row * NHEAD + wav * 2]     = d0;
        ad1[row * NHEAD + wav * 2 + 1] = d1;
      }
    }
  }
}

// ---------------- CSR build ----------------
__global__ void count_kernel(const int* __restrict__ ei, int* __restrict__ deg) {
  int e = blockIdx.x * blockDim.x + threadIdx.x;
  if (e >= EL) return;
  int dst = (e < N_EDGES) ? ei[N_EDGES + e] : (e - N_EDGES);
  atomicAdd(&deg[dst], 1);
}

__global__ __launch_bounds__(1024) void scan_part_kernel(
    const int* __restrict__ deg, int* __restrict__ off, int* __restrict__ btot) {
  __shared__ int warp_sums[16];
  const int tid = threadIdx.x;
  const int lane = tid & 63, wid = tid >> 6;
  int i = blockIdx.x * 1024 + tid;
  int v = (i < N_NODES) ? deg[i] : 0;
  int x = v;
#pragma unroll
  for (int o = 1; o < 64; o <<= 1) {
    int y = __shfl_up(x, o, 64);
    if (lane >= o) x += y;
  }
  if (lane == 63) warp_sums[wid] = x;
  __syncthreads();
  if (wid == 0) {
    int ws = (lane < 16) ? warp_sums[lane] : 0;
#pragma unroll
    for (int o = 1; o < 16; o <<= 1) {
      int y = __shfl_up(ws, o, 64);
      if (lane >= o) ws += y;
    }
    if (lane < 16) warp_sums[lane] = ws;
  }
  __syncthreads();
  int wprefix = (wid > 0) ? warp_sums[wid - 1] : 0;
  if (i < N_NODES) off[i] = wprefix + x - v;
  if (tid == 1023) btot[blockIdx.x] = warp_sums[15];
}

__global__ __launch_bounds__(64) void scan_tops_kernel(
    const int* __restrict__ btot, int* __restrict__ bo) {
  int lane = threadIdx.x;
  int v = (lane < NB_SCAN) ? btot[lane] : 0;
  int x = v;
#pragma unroll
  for (int o = 1; o < 64; o <<= 1) {
    int y = __shfl_up(x, o, 64);
    if (lane >= o) x += y;
  }
  if (lane < NB_SCAN) bo[lane] = x - v;  // exclusive
}

__global__ void scan_add_kernel(int* __restrict__ off, const int* __restrict__ bo) {
  int i = blockIdx.x * blockDim.x + threadIdx.x;
  if (i > N_NODES) return;
  if (i == N_NODES) off[i] = EL;
  else off[i] += bo[i >> 10];
}

// ---- fill CSR (pure; attention numerators computed inline in agg1) ----
__global__ void fill_kernel(const int* __restrict__ ei, const int* __restrict__ off,
                            int* __restrict__ cur, int* __restrict__ csr) {
  int e = blockIdx.x * blockDim.x + threadIdx.x;
  if (e >= EL) return;
  int src, dst;
  if (e < N_EDGES) { src = ei[e]; dst = ei[N_EDGES + e]; }
  else { src = e - N_EDGES; dst = src; }
  int pos = atomicAdd(&cur[dst], 1);
  csr[off[dst] + pos] = src;
}

// ---- layer-1 aggregation (inline no-max softmax) + FUSED layer-2 linear ----
// 4 nodes/block, 64 thr/node (one wave per node), 8B gathers, 4-unroll.
// Logits e = as+ad ~ N(0,~1.1): |e| < ~7 over 6.8M samples -> exp safe in fp32.
__global__ __launch_bounds__(256) void agg1_kernel(
    const __half* __restrict__ h1h, const float* __restrict__ as1,
    const float* __restrict__ ad1, const int* __restrict__ off,
    const int* __restrict__ csr, const float* __restrict__ b1,
    const float* __restrict__ W2, const float* __restrict__ att_s2,
    const float* __restrict__ att_d2, float* __restrict__ h2,
    float* __restrict__ as2, float* __restrict__ ad2) {
  __shared__ float W2s[HID * 11];  // stride-11 pad (bank spread)
  {
    int tid = threadIdx.x;
    for (int i = tid; i < HID * 10; i += 256)
      W2s[(i / 10) * 11 + (i % 10)] = W2[i];
  }
  __syncthreads();
  const int t = threadIdx.x & 63;
  const int n = blockIdx.x * 4 + (threadIdx.x >> 6);
  if (n >= N_NODES) return;
  const int head = t >> 3;  // 4 channels (t*4..t*4+3) all inside one head
  const float adn = ad1[n * NHEAD + head];
  const int j0 = off[n], j1 = off[n + 1];
  float a0 = 0.f, a1 = 0.f, a2 = 0.f, a3 = 0.f, den = 0.f;
  int j = j0;
  for (; j + 3 < j1; j += 4) {
    int s[4];
    float pw[4];
    H4 v[4];
#pragma unroll
    for (int q = 0; q < 4; ++q) s[q] = csr[j + q];
#pragma unroll
    for (int q = 0; q < 4; ++q) {
      float e = as1[s[q] * NHEAD + head] + adn;
      e = (e >= 0.f) ? e : 0.2f * e;
      pw[q] = __expf(e);
      v[q] = *(const H4*)&h1h[s[q] * HID + t * 4];
    }
#pragma unroll
    for (int q = 0; q < 4; ++q) {
      float2 fa = __half22float2(v[q].a), fb = __half22float2(v[q].b);
      den += pw[q];
      a0 += pw[q] * fa.x;
      a1 += pw[q] * fa.y;
      a2 += pw[q] * fb.x;
      a3 += pw[q] * fb.y;
    }
  }
  for (; j < j1; ++j) {
    int s0 = csr[j];
    float e = as1[s0 * NHEAD + head] + adn;
    e = (e >= 0.f) ? e : 0.2f * e;
    float p0 = __expf(e);
    H4 v0 = *(const H4*)&h1h[s0 * HID + t * 4];
    float2 fa = __half22float2(v0.a), fb = __half22float2(v0.b);
    den += p0;
    a0 += p0 * fa.x;
    a1 += p0 * fa.y;
    a2 += p0 * fb.x;
    a3 += p0 * fb.y;
  }
  float rden = 1.f / (den + 1e-16f);
  float4 bv = *(const float4*)&b1[t * 4];
  float vv[4];
  vv[0] = a0 * rden + bv.x;
  vv[1] = a1 * rden + bv.y;
  vv[2] = a2 * rden + bv.z;
  vv[3] = a3 * rden + bv.w;
#pragma unroll
  for (int c = 0; c < 4; ++c) vv[c] = (vv[c] > 0.f) ? vv[c] : (__expf(vv[c]) - 1.f);
  // fused layer-2 linear: h2[n][k] = sum_c o1[n][c]*W2[c][k], wave-reduced
  float hk[10];
#pragma unroll
  for (int k = 0; k < 10; ++k) {
    float pk = vv[0] * W2s[(t * 4 + 0) * 11 + k] +
               vv[1] * W2s[(t * 4 + 1) * 11 + k] +
               vv[2] * W2s[(t * 4 + 2) * 11 + k] +
               vv[3] * W2s[(t * 4 + 3) * 11 + k];
#pragma unroll
    for (int o = 32; o >= 1; o >>= 1) pk += __shfl_xor(pk, o, 64);
    hk[k] = pk;
  }
  if (t == 0) {
    float s = 0.f, d = 0.f;
#pragma unroll
    for (int k = 0; k < 10; ++k) {
      h2[n * 10 + k] = hk[k];
      s += hk[k] * att_s2[k];
      d += hk[k] * att_d2[k];
    }
    as2[n] = s;
    ad2[n] = d;
  }
}

// ---- layer-2 aggregation: 16-lane sub-groups, 16 nodes/block ----
__global__ __launch_bounds__(256) void agg2_kernel(
    const float* __restrict__ h2, const float* __restrict__ as2,
    const float* __restrict__ ad2, const int* __restrict__ off,
    const int* __restrict__ csr, const float* __restrict__ b2,
    float* __restrict__ out) {
  int g = threadIdx.x >> 4, l = threadIdx.x & 15;
  int n = blockIdx.x * 16 + g;
  if (n >= N_NODES) return;
  float adn = ad2[n];
  int j0 = off[n], j1 = off[n + 1];
  float acc = 0.f, den = 0.f;
  int j = j0;
  for (; j + 1 < j1; j += 2) {
    int s0 = csr[j], s1 = csr[j + 1];
    float e0 = as2[s0] + adn, e1 = as2[s1] + adn;
    e0 = (e0 >= 0.f) ? e0 : 0.2f * e0;
    e1 = (e1 >= 0.f) ? e1 : 0.2f * e1;
    float p0 = __expf(e0), p1v = __expf(e1);
    den += p0 + p1v;
    if (l < 10) acc += p0 * h2[s0 * 10 + l] + p1v * h2[s1 * 10 + l];
  }
  if (j < j1) {
    int s0 = csr[j];
    float e0 = as2[s0] + adn;
    e0 = (e0 >= 0.f) ? e0 : 0.2f * e0;
    float p0 = __expf(e0);
    den += p0;
    if (l < 10) acc += p0 * h2[s0 * 10 + l];
  }
  if (l < 10) out[n * 10 + l] = acc / (den + 1e-16f) + b2[l];
}

extern "C" void kernel_launch(void* const* d_in, const int* in_sizes, int n_in,
                              void* d_out, int out_size, void* d_ws, size_t ws_size,
                              hipStream_t stream) {
  const float* x    = (const float*)d_in[0];
  const int*   ei   = (const int*)d_in[1];
  const float* W1   = (const float*)d_in[2];
  const float* as1w = (const float*)d_in[3];
  const float* ad1w = (const float*)d_in[4];
  const float* b1   = (const float*)d_in[5];
  const float* W2   = (const float*)d_in[6];
  const float* as2w = (const float*)d_in[7];
  const float* ad2w = (const float*)d_in[8];
  const float* b2   = (const float*)d_in[9];
  float* out = (float*)d_out;

  char* p = (char*)d_ws;
  __half* h1h = (__half*)p; p += (size_t)N_NODES * HID * 2;
  float* a_s1 = (float*)p; p += (size_t)N_NODES * NHEAD * 4;
  float* a_d1 = (float*)p; p += (size_t)N_NODES * NHEAD * 4;
  float* h2   = (float*)p; p += (size_t)N_NODES * 10 * 4;
  float* a_s2 = (float*)p; p += (size_t)N_NODES * 4;
  float* a_d2 = (float*)p; p += (size_t)N_NODES * 4;
  short* Wh   = (short*)p; p += (size_t)KSTEPS * 16 * 64 * 8 * 2;
  short* Wl   = (short*)p; p += (size_t)KSTEPS * 16 * 64 * 8 * 2;
  int* deg    = (int*)p;   p += (size_t)N_NODES * 4;
  int* cur    = (int*)p;   p += (size_t)N_NODES * 4;
  int* off    = (int*)p;   p += (size_t)(N_NODES + 1) * 4;
  int* csr    = (int*)p;   p += (size_t)EL * 4;
  int* btot   = (int*)p;   p += 64 * 4;
  int* bo     = (int*)p;   p += 64 * 4;

  prep_kernel<<<768, 256, 0, stream>>>(W1, Wh, Wl);
  gemm1_mfma_kernel<<<(N_NODES + 63) / 64, 256, 0, stream>>>(
      x, Wh, Wl, h1h, as1w, ad1w, a_s1, a_d1);
  hipMemsetAsync(deg, 0, (size_t)N_NODES * 2 * 4, stream);  // deg + cur (adjacent)
  count_kernel<<<(EL + 255) / 256, 256, 0, stream>>>(ei, deg);
  scan_part_kernel<<<NB_SCAN, 1024, 0, stream>>>(deg, off, btot);
  scan_tops_kernel<<<1, 64, 0, stream>>>(btot, bo);
  scan_add_kernel<<<(N_NODES + 256) / 256, 256, 0, stream>>>(off, bo);
  fill_kernel<<<(EL + 255) / 256, 256, 0, stream>>>(ei, off, cur, csr);
  agg1_kernel<<<(N_NODES + 3) / 4, 256, 0, stream>>>(
      h1h, a_s1, a_d1, off, csr, b1, W2, as2w, ad2w, h2, a_s2, a_d2);
  agg2_kernel<<<(N_NODES + 15) / 16, 256, 0, stream>>>(h2, a_s2, a_d2, off, csr, b2, out);
}

// Round 16
// 281.263 us; speedup vs baseline: 1.9429x; 1.7043x over previous
//
#include <hip/hip_runtime.h>
#include <hip/hip_fp16.h>

#define N_NODES 50000
#define N_EDGES 800000
#define EL (N_EDGES + N_NODES) /* 850000 */
#define F_IN 767
#define HID 256
#define NHEAD 8
#define KSTEPS 24 /* ceil(767/32) */
#define NCH 12    /* 64-k chunks */
#define NB_SCAN 49 /* ceil(50000/1024) */

typedef __attribute__((ext_vector_type(8))) short short8;
typedef __attribute__((ext_vector_type(4))) float f32x4;

static __device__ __forceinline__ unsigned short f2bf(float f) {
  unsigned int u = __float_as_uint(f);
  unsigned int r = (u + 0x7fffu + ((u >> 16) & 1u)) >> 16;
  return (unsigned short)r;
}
static __device__ __forceinline__ float bf2f(unsigned short h) {
  return __uint_as_float(((unsigned int)h) << 16);
}

// ---- prep: split W into bf16 hi/lo, repack to MFMA fragment order; also
//      zeroes deg/cur (fused memset — saves a dispatch).
__global__ __launch_bounds__(256) void prep_kernel(
    const float* __restrict__ W, short* __restrict__ Wh, short* __restrict__ Wl,
    int* __restrict__ deg, int* __restrict__ cur) {
  int idx = blockIdx.x * 256 + threadIdx.x;  // 768*256 = 196608 threads
  if (idx < N_NODES) { deg[idx] = 0; cur[idx] = 0; }
  int k = idx >> 8, n = idx & 255;
  float v = (k < F_IN) ? W[k * HID + n] : 0.f;
  unsigned short h = f2bf(v);
  float lf = v - bf2f(h);
  unsigned short lo = f2bf(lf);
  int ks = k >> 5, oct = (k >> 3) & 3, j = k & 7;
  int nf = n >> 4;
  int l = (n & 15) | (oct << 4);
  int addr = ((ks * 16 + nf) * 64 + l) * 8 + j;
  Wh[addr] = (short)h;
  Wl[addr] = (short)lo;
}

// ---- GEMM1 (R12 champion, VERIFIED 106us x3): A in bf16 single plane,
//      B split hi/lo (2-pass MFMA), BK=64 dbuf LDS (16KB), XOR-swizzle,
//      depth-2 chunk prefetch, B prefetch 1 ks ahead, fused as1/ad1 epilogue.
//      (256,2) is the ONLY viable bound: measured VGPR caps are ~512/(2N)
//      (N=2 -> 128 >= 120 used; N=3 -> 84 spills; N=4 -> 64 catastrophic).
__global__ __launch_bounds__(256, 2) void gemm1_mfma_kernel(
    const float* __restrict__ x, const short* __restrict__ Wh,
    const short* __restrict__ Wl, __half* __restrict__ h1h,
    const float* __restrict__ att_s, const float* __restrict__ att_d,
    float* __restrict__ as1, float* __restrict__ ad1) {
  __shared__ __align__(16) short Ah[2][2][2048];
  const int tid = threadIdx.x;
  const int lane = tid & 63, wav = tid >> 6;
  const int m0 = blockIdx.x * 64;
  const int m_local = tid >> 2, oct = tid & 3;
  const int gm = m0 + m_local;
  const bool vrow = (gm < N_NODES);
  const long xbase = (long)gm * F_IN;
  const int wu0 = ((m_local >> 4) * 64) + ((m_local & 15) | (oct << 4));
  const int wu = wu0 ^ ((((unsigned)wu0 >> 4) & 3) << 1);

  float atts[4], attd[4];
#pragma unroll
  for (int nf = 0; nf < 4; ++nf) {
    int c = wav * 64 + nf * 16 + (lane & 15);
    atts[nf] = att_s[c];
    attd[nf] = att_d[c];
  }

  f32x4 acc[4][4];
#pragma unroll
  for (int i = 0; i < 4; ++i)
#pragma unroll
    for (int j = 0; j < 4; ++j) acc[i][j] = (f32x4){0.f, 0.f, 0.f, 0.f};

  // depth-2 chunk prefetch (16 floats each: 2 k-steps)
  float xc[16], xn[16];
  {
    int kb = oct * 8;
    if (vrow) {
#pragma unroll
      for (int ki = 0; ki < 2; ++ki)
#pragma unroll
        for (int j = 0; j < 8; ++j) {
          xc[ki * 8 + j] = x[xbase + kb + ki * 32 + j];
          xn[ki * 8 + j] = x[xbase + 64 + kb + ki * 32 + j];
        }
    } else {
#pragma unroll
      for (int j = 0; j < 16; ++j) { xc[j] = 0.f; xn[j] = 0.f; }
    }
  }
  // B prefetch for ks=0
  short8 bhc[4], blc[4];
  {
    const short* wb = Wh + ((wav * 4) * 64 + lane) * 8;
    const short* wbl = Wl + ((wav * 4) * 64 + lane) * 8;
#pragma unroll
    for (int nf = 0; nf < 4; ++nf) {
      bhc[nf] = *(const short8*)(wb + nf * 512);
      blc[nf] = *(const short8*)(wbl + nf * 512);
    }
  }

#pragma unroll 2
  for (int c = 0; c < NCH; ++c) {
    // convert both k-steps of chunk c -> LDS buf[c&1] (bf16 hi only)
#pragma unroll
    for (int ki = 0; ki < 2; ++ki) {
      short8 hi8;
#pragma unroll
      for (int j = 0; j < 8; ++j) hi8[j] = (short)f2bf(xc[ki * 8 + j]);
      *(short8*)&Ah[c & 1][ki][wu * 8] = hi8;
    }
    // rotate prefetch; issue x loads for chunk c+2
    {
#pragma unroll
      for (int j = 0; j < 16; ++j) xc[j] = xn[j];
      int s = c + 2;
      if (s < NCH - 1) {
        int kb = s * 64 + oct * 8;
        if (vrow) {
#pragma unroll
          for (int ki = 0; ki < 2; ++ki)
#pragma unroll
            for (int j = 0; j < 8; ++j) xn[ki * 8 + j] = x[xbase + kb + ki * 32 + j];
        } else {
#pragma unroll
          for (int j = 0; j < 16; ++j) xn[j] = 0.f;
        }
      } else if (s == NCH - 1) {
        int kb = s * 64 + oct * 8;
#pragma unroll
        for (int ki = 0; ki < 2; ++ki)
#pragma unroll
          for (int j = 0; j < 8; ++j) {
            int k = kb + ki * 32 + j;
            xn[ki * 8 + j] = (vrow && k < F_IN) ? x[xbase + k] : 0.f;
          }
      }
    }
    __syncthreads();
#pragma unroll
    for (int ki = 0; ki < 2; ++ki) {
      const int ksg = c * 2 + ki;
      short8 ah[4];
#pragma unroll
      for (int mf = 0; mf < 4; ++mf) {
        int u = mf * 64 + lane;
        int us = u ^ ((((unsigned)u >> 4) & 3) << 1);
        ah[mf] = *(short8*)&Ah[c & 1][ki][us * 8];
      }
      // B prefetch for ksg+1 (in flight across the MFMA block)
      short8 bhn[4], bln[4];
      if (ksg + 1 < KSTEPS) {
        const short* wb = Wh + (((ksg + 1) * 16 + wav * 4) * 64 + lane) * 8;
        const short* wbl = Wl + (((ksg + 1) * 16 + wav * 4) * 64 + lane) * 8;
#pragma unroll
        for (int nf = 0; nf < 4; ++nf) {
          bhn[nf] = *(const short8*)(wb + nf * 512);
          bln[nf] = *(const short8*)(wbl + nf * 512);
        }
      }
      // 2 passes of 16 independent MFMAs (A-hi x B-hi, A-hi x B-lo)
#pragma unroll
      for (int mf = 0; mf < 4; ++mf)
#pragma unroll
        for (int nf = 0; nf < 4; ++nf)
          acc[mf][nf] = __builtin_amdgcn_mfma_f32_16x16x32_bf16(ah[mf], bhc[nf], acc[mf][nf], 0, 0, 0);
#pragma unroll
      for (int mf = 0; mf < 4; ++mf)
#pragma unroll
        for (int nf = 0; nf < 4; ++nf)
          acc[mf][nf] = __builtin_amdgcn_mfma_f32_16x16x32_bf16(ah[mf], blc[nf], acc[mf][nf], 0, 0, 0);
#pragma unroll
      for (int nf = 0; nf < 4; ++nf) {
        bhc[nf] = bhn[nf];
        blc[nf] = bln[nf];
      }
    }
  }

  // epilogue: h1 (fp16) store + fused as1/ad1 reduction
  const int r0 = (lane >> 4) * 4, cn = lane & 15;
#pragma unroll
  for (int mf = 0; mf < 4; ++mf) {
    int rowb = m0 + mf * 16 + r0;
#pragma unroll
    for (int rr = 0; rr < 4; ++rr) {
      int row = rowb + rr;
      bool ok = (row < N_NODES);
      if (ok) {
#pragma unroll
        for (int nf = 0; nf < 4; ++nf)
          h1h[(long)row * HID + wav * 64 + nf * 16 + cn] =
              __float2half_rn(acc[mf][nf][rr]);
      }
      float s0 = acc[mf][0][rr] * atts[0] + acc[mf][1][rr] * atts[1];
      float s1 = acc[mf][2][rr] * atts[2] + acc[mf][3][rr] * atts[3];
      float d0 = acc[mf][0][rr] * attd[0] + acc[mf][1][rr] * attd[1];
      float d1 = acc[mf][2][rr] * attd[2] + acc[mf][3][rr] * attd[3];
#pragma unroll
      for (int o = 1; o < 16; o <<= 1) {
        s0 += __shfl_xor(s0, o, 64);
        s1 += __shfl_xor(s1, o, 64);
        d0 += __shfl_xor(d0, o, 64);
        d1 += __shfl_xor(d1, o, 64);
      }
      if (ok && cn == 0) {
        as1[row * NHEAD + wav * 2]     = s0;
        as1[row * NHEAD + wav * 2 + 1] = s1;
        ad1[row * NHEAD + wav * 2]     = d0;
        ad1[row * NHEAD + wav * 2 + 1] = d1;
      }
    }
  }
}

// ---------------- CSR build ----------------
__global__ void count_kernel(const int* __restrict__ ei, int* __restrict__ deg) {
  int e = blockIdx.x * blockDim.x + threadIdx.x;
  if (e >= EL) return;
  int dst = (e < N_EDGES) ? ei[N_EDGES + e] : (e - N_EDGES);
  atomicAdd(&deg[dst], 1);
}

__global__ __launch_bounds__(1024) void scan_part_kernel(
    const int* __restrict__ deg, int* __restrict__ off, int* __restrict__ btot) {
  __shared__ int warp_sums[16];
  const int tid = threadIdx.x;
  const int lane = tid & 63, wid = tid >> 6;
  int i = blockIdx.x * 1024 + tid;
  int v = (i < N_NODES) ? deg[i] : 0;
  int x = v;
#pragma unroll
  for (int o = 1; o < 64; o <<= 1) {
    int y = __shfl_up(x, o, 64);
    if (lane >= o) x += y;
  }
  if (lane == 63) warp_sums[wid] = x;
  __syncthreads();
  if (wid == 0) {
    int ws = (lane < 16) ? warp_sums[lane] : 0;
#pragma unroll
    for (int o = 1; o < 16; o <<= 1) {
      int y = __shfl_up(ws, o, 64);
      if (lane >= o) ws += y;
    }
    if (lane < 16) warp_sums[lane] = ws;
  }
  __syncthreads();
  int wprefix = (wid > 0) ? warp_sums[wid - 1] : 0;
  if (i < N_NODES) off[i] = wprefix + x - v;
  if (tid == 1023) btot[blockIdx.x] = warp_sums[15];
}

__global__ __launch_bounds__(64) void scan_tops_kernel(
    const int* __restrict__ btot, int* __restrict__ bo) {
  int lane = threadIdx.x;
  int v = (lane < NB_SCAN) ? btot[lane] : 0;
  int x = v;
#pragma unroll
  for (int o = 1; o < 64; o <<= 1) {
    int y = __shfl_up(x, o, 64);
    if (lane >= o) x += y;
  }
  if (lane < NB_SCAN) bo[lane] = x - v;  // exclusive
}

__global__ void scan_add_kernel(int* __restrict__ off, const int* __restrict__ bo) {
  int i = blockIdx.x * blockDim.x + threadIdx.x;
  if (i > N_NODES) return;
  if (i == N_NODES) off[i] = EL;
  else off[i] += bo[i >> 10];
}

// ---- fill CSR (pure; attention numerators computed inline in agg1) ----
__global__ void fill_kernel(const int* __restrict__ ei, const int* __restrict__ off,
                            int* __restrict__ cur, int* __restrict__ csr) {
  int e = blockIdx.x * blockDim.x + threadIdx.x;
  if (e >= EL) return;
  int src, dst;
  if (e < N_EDGES) { src = ei[e]; dst = ei[N_EDGES + e]; }
  else { src = e - N_EDGES; dst = src; }
  int pos = atomicAdd(&cur[dst], 1);
  csr[off[dst] + pos] = src;
}

// ---- layer-1 aggregation (inline no-max softmax) + FUSED layer-2 linear ----
// 8 nodes/block, 32 thr/node, 16B h1 gathers (8 ch/thread), 4-edge unroll.
// Logits e = as+ad ~ N(0,~1.1): |e| < ~7 over 6.8M samples -> exp safe in fp32.
__global__ __launch_bounds__(256) void agg1_kernel(
    const __half* __restrict__ h1h, const float* __restrict__ as1,
    const float* __restrict__ ad1, const int* __restrict__ off,
    const int* __restrict__ csr, const float* __restrict__ b1,
    const float* __restrict__ W2, const float* __restrict__ att_s2,
    const float* __restrict__ att_d2, float* __restrict__ h2,
    float* __restrict__ as2, float* __restrict__ ad2) {
  __shared__ float W2s[HID * 11];  // stride-11 pad (bank spread)
  {
    int tid = threadIdx.x;
    for (int i = tid; i < HID * 10; i += 256)
      W2s[(i / 10) * 11 + (i % 10)] = W2[i];
  }
  __syncthreads();
  const int t = threadIdx.x & 31;
  const int n = blockIdx.x * 8 + (threadIdx.x >> 5);
  if (n >= N_NODES) return;
  const int head = t >> 2;  // channels t*8..t*8+7 all inside head t/4
  const float adn = ad1[n * NHEAD + head];
  const int j0 = off[n], j1 = off[n + 1];
  float a[8] = {0.f, 0.f, 0.f, 0.f, 0.f, 0.f, 0.f, 0.f};
  float den = 0.f;
  int j = j0;
  for (; j + 3 < j1; j += 4) {
    int s[4];
    float pw[4];
    float4 v[4];
#pragma unroll
    for (int q = 0; q < 4; ++q) s[q] = csr[j + q];
#pragma unroll
    for (int q = 0; q < 4; ++q) {
      float e = as1[s[q] * NHEAD + head] + adn;
      e = (e >= 0.f) ? e : 0.2f * e;
      pw[q] = __expf(e);
      v[q] = *(const float4*)&h1h[s[q] * HID + t * 8];
    }
#pragma unroll
    for (int q = 0; q < 4; ++q) {
      const __half2* hp = (const __half2*)&v[q];
      den += pw[q];
#pragma unroll
      for (int c2 = 0; c2 < 4; ++c2) {
        float2 f = __half22float2(hp[c2]);
        a[2 * c2]     += pw[q] * f.x;
        a[2 * c2 + 1] += pw[q] * f.y;
      }
    }
  }
  for (; j < j1; ++j) {
    int s0 = csr[j];
    float e = as1[s0 * NHEAD + head] + adn;
    e = (e >= 0.f) ? e : 0.2f * e;
    float p0 = __expf(e);
    float4 v0 = *(const float4*)&h1h[s0 * HID + t * 8];
    const __half2* hp = (const __half2*)&v0;
    den += p0;
#pragma unroll
    for (int c2 = 0; c2 < 4; ++c2) {
      float2 f = __half22float2(hp[c2]);
      a[2 * c2]     += p0 * f.x;
      a[2 * c2 + 1] += p0 * f.y;
    }
  }
  float rden = 1.f / (den + 1e-16f);
  float4 bv0 = *(const float4*)&b1[t * 8];
  float4 bv1 = *(const float4*)&b1[t * 8 + 4];
  float vv[8];
  vv[0] = a[0] * rden + bv0.x;
  vv[1] = a[1] * rden + bv0.y;
  vv[2] = a[2] * rden + bv0.z;
  vv[3] = a[3] * rden + bv0.w;
  vv[4] = a[4] * rden + bv1.x;
  vv[5] = a[5] * rden + bv1.y;
  vv[6] = a[6] * rden + bv1.z;
  vv[7] = a[7] * rden + bv1.w;
#pragma unroll
  for (int c = 0; c < 8; ++c) vv[c] = (vv[c] > 0.f) ? vv[c] : (__expf(vv[c]) - 1.f);
  // fused layer-2 linear: h2[n][k] = sum_c o1[n][c]*W2[c][k], 32-lane reduce
  float hk[10];
#pragma unroll
  for (int k = 0; k < 10; ++k) {
    float pk = 0.f;
#pragma unroll
    for (int c = 0; c < 8; ++c) pk += vv[c] * W2s[(t * 8 + c) * 11 + k];
#pragma unroll
    for (int o = 16; o >= 1; o >>= 1) pk += __shfl_xor(pk, o, 64);
    hk[k] = pk;
  }
  if (t == 0) {
    float s = 0.f, d = 0.f;
#pragma unroll
    for (int k = 0; k < 10; ++k) {
      h2[n * 10 + k] = hk[k];
      s += hk[k] * att_s2[k];
      d += hk[k] * att_d2[k];
    }
    as2[n] = s;
    ad2[n] = d;
  }
}

// ---- layer-2 aggregation: 16-lane sub-groups, 16 nodes/block ----
__global__ __launch_bounds__(256) void agg2_kernel(
    const float* __restrict__ h2, const float* __restrict__ as2,
    const float* __restrict__ ad2, const int* __restrict__ off,
    const int* __restrict__ csr, const float* __restrict__ b2,
    float* __restrict__ out) {
  int g = threadIdx.x >> 4, l = threadIdx.x & 15;
  int n = blockIdx.x * 16 + g;
  if (n >= N_NODES) return;
  float adn = ad2[n];
  int j0 = off[n], j1 = off[n + 1];
  float acc = 0.f, den = 0.f;
  int j = j0;
  for (; j + 1 < j1; j += 2) {
    int s0 = csr[j], s1 = csr[j + 1];
    float e0 = as2[s0] + adn, e1 = as2[s1] + adn;
    e0 = (e0 >= 0.f) ? e0 : 0.2f * e0;
    e1 = (e1 >= 0.f) ? e1 : 0.2f * e1;
    float p0 = __expf(e0), p1v = __expf(e1);
    den += p0 + p1v;
    if (l < 10) acc += p0 * h2[s0 * 10 + l] + p1v * h2[s1 * 10 + l];
  }
  if (j < j1) {
    int s0 = csr[j];
    float e0 = as2[s0] + adn;
    e0 = (e0 >= 0.f) ? e0 : 0.2f * e0;
    float p0 = __expf(e0);
    den += p0;
    if (l < 10) acc += p0 * h2[s0 * 10 + l];
  }
  if (l < 10) out[n * 10 + l] = acc / (den + 1e-16f) + b2[l];
}

extern "C" void kernel_launch(void* const* d_in, const int* in_sizes, int n_in,
                              void* d_out, int out_size, void* d_ws, size_t ws_size,
                              hipStream_t stream) {
  const float* x    = (const float*)d_in[0];
  const int*   ei   = (const int*)d_in[1];
  const float* W1   = (const float*)d_in[2];
  const float* as1w = (const float*)d_in[3];
  const float* ad1w = (const float*)d_in[4];
  const float* b1   = (const float*)d_in[5];
  const float* W2   = (const float*)d_in[6];
  const float* as2w = (const float*)d_in[7];
  const float* ad2w = (const float*)d_in[8];
  const float* b2   = (const float*)d_in[9];
  float* out = (float*)d_out;

  char* p = (char*)d_ws;
  __half* h1h = (__half*)p; p += (size_t)N_NODES * HID * 2;
  float* a_s1 = (float*)p; p += (size_t)N_NODES * NHEAD * 4;
  float* a_d1 = (float*)p; p += (size_t)N_NODES * NHEAD * 4;
  float* h2   = (float*)p; p += (size_t)N_NODES * 10 * 4;
  float* a_s2 = (float*)p; p += (size_t)N_NODES * 4;
  float* a_d2 = (float*)p; p += (size_t)N_NODES * 4;
  short* Wh   = (short*)p; p += (size_t)KSTEPS * 16 * 64 * 8 * 2;
  short* Wl   = (short*)p; p += (size_t)KSTEPS * 16 * 64 * 8 * 2;
  int* deg    = (int*)p;   p += (size_t)N_NODES * 4;
  int* cur    = (int*)p;   p += (size_t)N_NODES * 4;
  int* off    = (int*)p;   p += (size_t)(N_NODES + 1) * 4;
  int* csr    = (int*)p;   p += (size_t)EL * 4;
  int* btot   = (int*)p;   p += 64 * 4;
  int* bo     = (int*)p;   p += 64 * 4;

  prep_kernel<<<768, 256, 0, stream>>>(W1, Wh, Wl, deg, cur);
  gemm1_mfma_kernel<<<(N_NODES + 63) / 64, 256, 0, stream>>>(
      x, Wh, Wl, h1h, as1w, ad1w, a_s1, a_d1);
  count_kernel<<<(EL + 255) / 256, 256, 0, stream>>>(ei, deg);
  scan_part_kernel<<<NB_SCAN, 1024, 0, stream>>>(deg, off, btot);
  scan_tops_kernel<<<1, 64, 0, stream>>>(btot, bo);
  scan_add_kernel<<<(N_NODES + 256) / 256, 256, 0, stream>>>(off, bo);
  fill_kernel<<<(EL + 255) / 256, 256, 0, stream>>>(ei, off, cur, csr);
  agg1_kernel<<<(N_NODES + 7) / 8, 256, 0, stream>>>(
      h1h, a_s1, a_d1, off, csr, b1, W2, as2w, ad2w, h2, a_s2, a_d2);
  agg2_kernel<<<(N_NODES + 15) / 16, 256, 0, stream>>>(h2, a_s2, a_d2, off, csr, b2, out);
}

// Round 17
// 278.965 us; speedup vs baseline: 1.9589x; 1.0082x over previous
//
#include <hip/hip_runtime.h>
#include <hip/hip_fp16.h>

#define N_NODES 50000
#define N_EDGES 800000
#define EL (N_EDGES + N_NODES) /* 850000 */
#define F_IN 767
#define HID 256
#define NHEAD 8
#define KSTEPS 24 /* ceil(767/32) */
#define NCH 12    /* 64-k chunks */
#define NB_SCAN 49 /* ceil(50000/1024) */

typedef __attribute__((ext_vector_type(8))) short short8;
typedef __attribute__((ext_vector_type(4))) float f32x4;

static __device__ __forceinline__ unsigned short f2bf(float f) {
  unsigned int u = __float_as_uint(f);
  unsigned int r = (u + 0x7fffu + ((u >> 16) & 1u)) >> 16;
  return (unsigned short)r;
}
static __device__ __forceinline__ float bf2f(unsigned short h) {
  return __uint_as_float(((unsigned int)h) << 16);
}

// ---- prep: split W into bf16 hi/lo, repack to MFMA fragment order; also
//      zeroes deg/cur (fused memset).
__global__ __launch_bounds__(256) void prep_kernel(
    const float* __restrict__ W, short* __restrict__ Wh, short* __restrict__ Wl,
    int* __restrict__ deg, int* __restrict__ cur) {
  int idx = blockIdx.x * 256 + threadIdx.x;  // 768*256 = 196608 threads
  if (idx < N_NODES) { deg[idx] = 0; cur[idx] = 0; }
  int k = idx >> 8, n = idx & 255;
  float v = (k < F_IN) ? W[k * HID + n] : 0.f;
  unsigned short h = f2bf(v);
  float lf = v - bf2f(h);
  unsigned short lo = f2bf(lf);
  int ks = k >> 5, oct = (k >> 3) & 3, j = k & 7;
  int nf = n >> 4;
  int l = (n & 15) | (oct << 4);
  int addr = ((ks * 16 + nf) * 64 + l) * 8 + j;
  Wh[addr] = (short)h;
  Wl[addr] = (short)lo;
}

// ---- GEMM1 (R12 structure; ONLY change vs R16: x-loads for chunk c+2 are
//      issued AFTER __syncthreads(), so the barrier's vmcnt(0) drain no
//      longer waits on a just-issued ~900cy HBM load — that drain is paid
//      one full compute phase later, i.e. ~free. Everything else identical.
//      (256,2) is the ONLY viable bound (VGPR cap ~512/(2N); need ~120).
__global__ __launch_bounds__(256, 2) void gemm1_mfma_kernel(
    const float* __restrict__ x, const short* __restrict__ Wh,
    const short* __restrict__ Wl, __half* __restrict__ h1h,
    const float* __restrict__ att_s, const float* __restrict__ att_d,
    float* __restrict__ as1, float* __restrict__ ad1) {
  __shared__ __align__(16) short Ah[2][2][2048];
  const int tid = threadIdx.x;
  const int lane = tid & 63, wav = tid >> 6;
  const int m0 = blockIdx.x * 64;
  const int m_local = tid >> 2, oct = tid & 3;
  const int gm = m0 + m_local;
  const bool vrow = (gm < N_NODES);
  const long xbase = (long)gm * F_IN;
  const int wu0 = ((m_local >> 4) * 64) + ((m_local & 15) | (oct << 4));
  const int wu = wu0 ^ ((((unsigned)wu0 >> 4) & 3) << 1);

  float atts[4], attd[4];
#pragma unroll
  for (int nf = 0; nf < 4; ++nf) {
    int c = wav * 64 + nf * 16 + (lane & 15);
    atts[nf] = att_s[c];
    attd[nf] = att_d[c];
  }

  f32x4 acc[4][4];
#pragma unroll
  for (int i = 0; i < 4; ++i)
#pragma unroll
    for (int j = 0; j < 4; ++j) acc[i][j] = (f32x4){0.f, 0.f, 0.f, 0.f};

  // depth-2 chunk prefetch (16 floats each: 2 k-steps)
  float xc[16], xn[16];
  {
    int kb = oct * 8;
    if (vrow) {
#pragma unroll
      for (int ki = 0; ki < 2; ++ki)
#pragma unroll
        for (int j = 0; j < 8; ++j) {
          xc[ki * 8 + j] = x[xbase + kb + ki * 32 + j];
          xn[ki * 8 + j] = x[xbase + 64 + kb + ki * 32 + j];
        }
    } else {
#pragma unroll
      for (int j = 0; j < 16; ++j) { xc[j] = 0.f; xn[j] = 0.f; }
    }
  }
  // B prefetch for ks=0
  short8 bhc[4], blc[4];
  {
    const short* wb = Wh + ((wav * 4) * 64 + lane) * 8;
    const short* wbl = Wl + ((wav * 4) * 64 + lane) * 8;
#pragma unroll
    for (int nf = 0; nf < 4; ++nf) {
      bhc[nf] = *(const short8*)(wb + nf * 512);
      blc[nf] = *(const short8*)(wbl + nf * 512);
    }
  }

#pragma unroll 2
  for (int c = 0; c < NCH; ++c) {
    // convert both k-steps of chunk c -> LDS buf[c&1] (bf16 hi only)
#pragma unroll
    for (int ki = 0; ki < 2; ++ki) {
      short8 hi8;
#pragma unroll
      for (int j = 0; j < 8; ++j) hi8[j] = (short)f2bf(xc[ki * 8 + j]);
      *(short8*)&Ah[c & 1][ki][wu * 8] = hi8;
    }
    __syncthreads();  // drains only loads issued >=1 chunk ago (~free)
    // rotate prefetch; issue x loads for chunk c+2 (drained NEXT barrier)
    {
#pragma unroll
      for (int j = 0; j < 16; ++j) xc[j] = xn[j];
      int s = c + 2;
      if (s < NCH - 1) {
        int kb = s * 64 + oct * 8;
        if (vrow) {
#pragma unroll
          for (int ki = 0; ki < 2; ++ki)
#pragma unroll
            for (int j = 0; j < 8; ++j) xn[ki * 8 + j] = x[xbase + kb + ki * 32 + j];
        } else {
#pragma unroll
          for (int j = 0; j < 16; ++j) xn[j] = 0.f;
        }
      } else if (s == NCH - 1) {
        int kb = s * 64 + oct * 8;
#pragma unroll
        for (int ki = 0; ki < 2; ++ki)
#pragma unroll
          for (int j = 0; j < 8; ++j) {
            int k = kb + ki * 32 + j;
            xn[ki * 8 + j] = (vrow && k < F_IN) ? x[xbase + k] : 0.f;
          }
      }
    }
#pragma unroll
    for (int ki = 0; ki < 2; ++ki) {
      const int ksg = c * 2 + ki;
      short8 ah[4];
#pragma unroll
      for (int mf = 0; mf < 4; ++mf) {
        int u = mf * 64 + lane;
        int us = u ^ ((((unsigned)u >> 4) & 3) << 1);
        ah[mf] = *(short8*)&Ah[c & 1][ki][us * 8];
      }
      // B prefetch for ksg+1 (in flight across the MFMA block)
      short8 bhn[4], bln[4];
      if (ksg + 1 < KSTEPS) {
        const short* wb = Wh + (((ksg + 1) * 16 + wav * 4) * 64 + lane) * 8;
        const short* wbl = Wl + (((ksg + 1) * 16 + wav * 4) * 64 + lane) * 8;
#pragma unroll
        for (int nf = 0; nf < 4; ++nf) {
          bhn[nf] = *(const short8*)(wb + nf * 512);
          bln[nf] = *(const short8*)(wbl + nf * 512);
        }
      }
      // 2 passes of 16 independent MFMAs (A-hi x B-hi, A-hi x B-lo)
#pragma unroll
      for (int mf = 0; mf < 4; ++mf)
#pragma unroll
        for (int nf = 0; nf < 4; ++nf)
          acc[mf][nf] = __builtin_amdgcn_mfma_f32_16x16x32_bf16(ah[mf], bhc[nf], acc[mf][nf], 0, 0, 0);
#pragma unroll
      for (int mf = 0; mf < 4; ++mf)
#pragma unroll
        for (int nf = 0; nf < 4; ++nf)
          acc[mf][nf] = __builtin_amdgcn_mfma_f32_16x16x32_bf16(ah[mf], blc[nf], acc[mf][nf], 0, 0, 0);
#pragma unroll
      for (int nf = 0; nf < 4; ++nf) {
        bhc[nf] = bhn[nf];
        blc[nf] = bln[nf];
      }
    }
  }

  // epilogue: h1 (fp16) store + fused as1/ad1 reduction
  const int r0 = (lane >> 4) * 4, cn = lane & 15;
#pragma unroll
  for (int mf = 0; mf < 4; ++mf) {
    int rowb = m0 + mf * 16 + r0;
#pragma unroll
    for (int rr = 0; rr < 4; ++rr) {
      int row = rowb + rr;
      bool ok = (row < N_NODES);
      if (ok) {
#pragma unroll
        for (int nf = 0; nf < 4; ++nf)
          h1h[(long)row * HID + wav * 64 + nf * 16 + cn] =
              __float2half_rn(acc[mf][nf][rr]);
      }
      float s0 = acc[mf][0][rr] * atts[0] + acc[mf][1][rr] * atts[1];
      float s1 = acc[mf][2][rr] * atts[2] + acc[mf][3][rr] * atts[3];
      float d0 = acc[mf][0][rr] * attd[0] + acc[mf][1][rr] * attd[1];
      float d1 = acc[mf][2][rr] * attd[2] + acc[mf][3][rr] * attd[3];
#pragma unroll
      for (int o = 1; o < 16; o <<= 1) {
        s0 += __shfl_xor(s0, o, 64);
        s1 += __shfl_xor(s1, o, 64);
        d0 += __shfl_xor(d0, o, 64);
        d1 += __shfl_xor(d1, o, 64);
      }
      if (ok && cn == 0) {
        as1[row * NHEAD + wav * 2]     = s0;
        as1[row * NHEAD + wav * 2 + 1] = s1;
        ad1[row * NHEAD + wav * 2]     = d0;
        ad1[row * NHEAD + wav * 2 + 1] = d1;
      }
    }
  }
}

// ---------------- CSR build ----------------
__global__ void count_kernel(const int* __restrict__ ei, int* __restrict__ deg) {
  int e = blockIdx.x * blockDim.x + threadIdx.x;
  if (e >= EL) return;
  int dst = (e < N_EDGES) ? ei[N_EDGES + e] : (e - N_EDGES);
  atomicAdd(&deg[dst], 1);
}

__global__ __launch_bounds__(1024) void scan_part_kernel(
    const int* __restrict__ deg, int* __restrict__ off, int* __restrict__ btot) {
  __shared__ int warp_sums[16];
  const int tid = threadIdx.x;
  const int lane = tid & 63, wid = tid >> 6;
  int i = blockIdx.x * 1024 + tid;
  int v = (i < N_NODES) ? deg[i] : 0;
  int x = v;
#pragma unroll
  for (int o = 1; o < 64; o <<= 1) {
    int y = __shfl_up(x, o, 64);
    if (lane >= o) x += y;
  }
  if (lane == 63) warp_sums[wid] = x;
  __syncthreads();
  if (wid == 0) {
    int ws = (lane < 16) ? warp_sums[lane] : 0;
#pragma unroll
    for (int o = 1; o < 16; o <<= 1) {
      int y = __shfl_up(ws, o, 64);
      if (lane >= o) ws += y;
    }
    if (lane < 16) warp_sums[lane] = ws;
  }
  __syncthreads();
  int wprefix = (wid > 0) ? warp_sums[wid - 1] : 0;
  if (i < N_NODES) off[i] = wprefix + x - v;
  if (tid == 1023) btot[blockIdx.x] = warp_sums[15];
}

__global__ __launch_bounds__(64) void scan_tops_kernel(
    const int* __restrict__ btot, int* __restrict__ bo) {
  int lane = threadIdx.x;
  int v = (lane < NB_SCAN) ? btot[lane] : 0;
  int x = v;
#pragma unroll
  for (int o = 1; o < 64; o <<= 1) {
    int y = __shfl_up(x, o, 64);
    if (lane >= o) x += y;
  }
  if (lane < NB_SCAN) bo[lane] = x - v;  // exclusive
}

__global__ void scan_add_kernel(int* __restrict__ off, const int* __restrict__ bo) {
  int i = blockIdx.x * blockDim.x + threadIdx.x;
  if (i > N_NODES) return;
  if (i == N_NODES) off[i] = EL;
  else off[i] += bo[i >> 10];
}

// ---- fill CSR (pure; attention numerators computed inline in agg1) ----
__global__ void fill_kernel(const int* __restrict__ ei, const int* __restrict__ off,
                            int* __restrict__ cur, int* __restrict__ csr) {
  int e = blockIdx.x * blockDim.x + threadIdx.x;
  if (e >= EL) return;
  int src, dst;
  if (e < N_EDGES) { src = ei[e]; dst = ei[N_EDGES + e]; }
  else { src = e - N_EDGES; dst = src; }
  int pos = atomicAdd(&cur[dst], 1);
  csr[off[dst] + pos] = src;
}

// ---- layer-1 aggregation (inline no-max softmax) + FUSED layer-2 linear ----
// 8 nodes/block, 32 thr/node, 16B h1 gathers (8 ch/thread), 4-edge unroll.
__global__ __launch_bounds__(256) void agg1_kernel(
    const __half* __restrict__ h1h, const float* __restrict__ as1,
    const float* __restrict__ ad1, const int* __restrict__ off,
    const int* __restrict__ csr, const float* __restrict__ b1,
    const float* __restrict__ W2, const float* __restrict__ att_s2,
    const float* __restrict__ att_d2, float* __restrict__ h2,
    float* __restrict__ as2, float* __restrict__ ad2) {
  __shared__ float W2s[HID * 11];  // stride-11 pad (bank spread)
  {
    int tid = threadIdx.x;
    for (int i = tid; i < HID * 10; i += 256)
      W2s[(i / 10) * 11 + (i % 10)] = W2[i];
  }
  __syncthreads();
  const int t = threadIdx.x & 31;
  const int n = blockIdx.x * 8 + (threadIdx.x >> 5);
  if (n >= N_NODES) return;
  const int head = t >> 2;  // channels t*8..t*8+7 all inside head t/4
  const float adn = ad1[n * NHEAD + head];
  const int j0 = off[n], j1 = off[n + 1];
  float a[8] = {0.f, 0.f, 0.f, 0.f, 0.f, 0.f, 0.f, 0.f};
  float den = 0.f;
  int j = j0;
  for (; j + 3 < j1; j += 4) {
    int s[4];
    float pw[4];
    float4 v[4];
#pragma unroll
    for (int q = 0; q < 4; ++q) s[q] = csr[j + q];
#pragma unroll
    for (int q = 0; q < 4; ++q) {
      float e = as1[s[q] * NHEAD + head] + adn;
      e = (e >= 0.f) ? e : 0.2f * e;
      pw[q] = __expf(e);
      v[q] = *(const float4*)&h1h[s[q] * HID + t * 8];
    }
#pragma unroll
    for (int q = 0; q < 4; ++q) {
      const __half2* hp = (const __half2*)&v[q];
      den += pw[q];
#pragma unroll
      for (int c2 = 0; c2 < 4; ++c2) {
        float2 f = __half22float2(hp[c2]);
        a[2 * c2]     += pw[q] * f.x;
        a[2 * c2 + 1] += pw[q] * f.y;
      }
    }
  }
  for (; j < j1; ++j) {
    int s0 = csr[j];
    float e = as1[s0 * NHEAD + head] + adn;
    e = (e >= 0.f) ? e : 0.2f * e;
    float p0 = __expf(e);
    float4 v0 = *(const float4*)&h1h[s0 * HID + t * 8];
    const __half2* hp = (const __half2*)&v0;
    den += p0;
#pragma unroll
    for (int c2 = 0; c2 < 4; ++c2) {
      float2 f = __half22float2(hp[c2]);
      a[2 * c2]     += p0 * f.x;
      a[2 * c2 + 1] += p0 * f.y;
    }
  }
  float rden = 1.f / (den + 1e-16f);
  float4 bv0 = *(const float4*)&b1[t * 8];
  float4 bv1 = *(const float4*)&b1[t * 8 + 4];
  float vv[8];
  vv[0] = a[0] * rden + bv0.x;
  vv[1] = a[1] * rden + bv0.y;
  vv[2] = a[2] * rden + bv0.z;
  vv[3] = a[3] * rden + bv0.w;
  vv[4] = a[4] * rden + bv1.x;
  vv[5] = a[5] * rden + bv1.y;
  vv[6] = a[6] * rden + bv1.z;
  vv[7] = a[7] * rden + bv1.w;
#pragma unroll
  for (int c = 0; c < 8; ++c) vv[c] = (vv[c] > 0.f) ? vv[c] : (__expf(vv[c]) - 1.f);
  // fused layer-2 linear: h2[n][k] = sum_c o1[n][c]*W2[c][k], 32-lane reduce
  float hk[10];
#pragma unroll
  for (int k = 0; k < 10; ++k) {
    float pk = 0.f;
#pragma unroll
    for (int c = 0; c < 8; ++c) pk += vv[c] * W2s[(t * 8 + c) * 11 + k];
#pragma unroll
    for (int o = 16; o >= 1; o >>= 1) pk += __shfl_xor(pk, o, 64);
    hk[k] = pk;
  }
  if (t == 0) {
    float s = 0.f, d = 0.f;
#pragma unroll
    for (int k = 0; k < 10; ++k) {
      h2[n * 10 + k] = hk[k];
      s += hk[k] * att_s2[k];
      d += hk[k] * att_d2[k];
    }
    as2[n] = s;
    ad2[n] = d;
  }
}

// ---- layer-2 aggregation: 16-lane sub-groups, 16 nodes/block ----
__global__ __launch_bounds__(256) void agg2_kernel(
    const float* __restrict__ h2, const float* __restrict__ as2,
    const float* __restrict__ ad2, const int* __restrict__ off,
    const int* __restrict__ csr, const float* __restrict__ b2,
    float* __restrict__ out) {
  int g = threadIdx.x >> 4, l = threadIdx.x & 15;
  int n = blockIdx.x * 16 + g;
  if (n >= N_NODES) return;
  float adn = ad2[n];
  int j0 = off[n], j1 = off[n + 1];
  float acc = 0.f, den = 0.f;
  int j = j0;
  for (; j + 1 < j1; j += 2) {
    int s0 = csr[j], s1 = csr[j + 1];
    float e0 = as2[s0] + adn, e1 = as2[s1] + adn;
    e0 = (e0 >= 0.f) ? e0 : 0.2f * e0;
    e1 = (e1 >= 0.f) ? e1 : 0.2f * e1;
    float p0 = __expf(e0), p1v = __expf(e1);
    den += p0 + p1v;
    if (l < 10) acc += p0 * h2[s0 * 10 + l] + p1v * h2[s1 * 10 + l];
  }
  if (j < j1) {
    int s0 = csr[j];
    float e0 = as2[s0] + adn;
    e0 = (e0 >= 0.f) ? e0 : 0.2f * e0;
    float p0 = __expf(e0);
    den += p0;
    if (l < 10) acc += p0 * h2[s0 * 10 + l];
  }
  if (l < 10) out[n * 10 + l] = acc / (den + 1e-16f) + b2[l];
}

extern "C" void kernel_launch(void* const* d_in, const int* in_sizes, int n_in,
                              void* d_out, int out_size, void* d_ws, size_t ws_size,
                              hipStream_t stream) {
  const float* x    = (const float*)d_in[0];
  const int*   ei   = (const int*)d_in[1];
  const float* W1   = (const float*)d_in[2];
  const float* as1w = (const float*)d_in[3];
  const float* ad1w = (const float*)d_in[4];
  const float* b1   = (const float*)d_in[5];
  const float* W2   = (const float*)d_in[6];
  const float* as2w = (const float*)d_in[7];
  const float* ad2w = (const float*)d_in[8];
  const float* b2   = (const float*)d_in[9];
  float* out = (float*)d_out;

  char* p = (char*)d_ws;
  __half* h1h = (__half*)p; p += (size_t)N_NODES * HID * 2;
  float* a_s1 = (float*)p; p += (size_t)N_NODES * NHEAD * 4;
  float* a_d1 = (float*)p; p += (size_t)N_NODES * NHEAD * 4;
  float* h2   = (float*)p; p += (size_t)N_NODES * 10 * 4;
  float* a_s2 = (float*)p; p += (size_t)N_NODES * 4;
  float* a_d2 = (float*)p; p += (size_t)N_NODES * 4;
  short* Wh   = (short*)p; p += (size_t)KSTEPS * 16 * 64 * 8 * 2;
  short* Wl   = (short*)p; p += (size_t)KSTEPS * 16 * 64 * 8 * 2;
  int* deg    = (int*)p;   p += (size_t)N_NODES * 4;
  int* cur    = (int*)p;   p += (size_t)N_NODES * 4;
  int* off    = (int*)p;   p += (size_t)(N_NODES + 1) * 4;
  int* csr    = (int*)p;   p += (size_t)EL * 4;
  int* btot   = (int*)p;   p += 64 * 4;
  int* bo     = (int*)p;   p += 64 * 4;

  prep_kernel<<<768, 256, 0, stream>>>(W1, Wh, Wl, deg, cur);
  gemm1_mfma_kernel<<<(N_NODES + 63) / 64, 256, 0, stream>>>(
      x, Wh, Wl, h1h, as1w, ad1w, a_s1, a_d1);
  count_kernel<<<(EL + 255) / 256, 256, 0, stream>>>(ei, deg);
  scan_part_kernel<<<NB_SCAN, 1024, 0, stream>>>(deg, off, btot);
  scan_tops_kernel<<<1, 64, 0, stream>>>(btot, bo);
  scan_add_kernel<<<(N_NODES + 256) / 256, 256, 0, stream>>>(off, bo);
  fill_kernel<<<(EL + 255) / 256, 256, 0, stream>>>(ei, off, cur, csr);
  agg1_kernel<<<(N_NODES + 7) / 8, 256, 0, stream>>>(
      h1h, a_s1, a_d1, off, csr, b1, W2, as2w, ad2w, h2, a_s2, a_d2);
  agg2_kernel<<<(N_NODES + 15) / 16, 256, 0, stream>>>(h2, a_s2, a_d2, off, csr, b2, out);
}

// Round 18
// 260.962 us; speedup vs baseline: 2.0941x; 1.0690x over previous
//
#include <hip/hip_runtime.h>
#include <hip/hip_fp16.h>

#define N_NODES 50000
#define N_EDGES 800000
#define EL (N_EDGES + N_NODES) /* 850000 */
#define F_IN 767
#define HID 256
#define NHEAD 8
#define KSTEPS 24 /* ceil(767/32) */
#define NCH 12    /* 64-k chunks */
#define NB_SCAN 49 /* ceil(50000/1024) */

typedef __attribute__((ext_vector_type(8))) short short8;
typedef __attribute__((ext_vector_type(4))) float f32x4;

static __device__ __forceinline__ unsigned short f2bf(float f) {
  unsigned int u = __float_as_uint(f);
  unsigned int r = (u + 0x7fffu + ((u >> 16) & 1u)) >> 16;
  return (unsigned short)r;
}
static __device__ __forceinline__ float bf2f(unsigned short h) {
  return __uint_as_float(((unsigned int)h) << 16);
}

// ---- prep: split W into bf16 hi/lo, repack to MFMA fragment order; also
//      zeroes deg/cur (fused memset).
__global__ __launch_bounds__(256) void prep_kernel(
    const float* __restrict__ W, short* __restrict__ Wh, short* __restrict__ Wl,
    int* __restrict__ deg, int* __restrict__ cur) {
  int idx = blockIdx.x * 256 + threadIdx.x;  // 768*256 = 196608 threads
  if (idx < N_NODES) { deg[idx] = 0; cur[idx] = 0; }
  int k = idx >> 8, n = idx & 255;
  float v = (k < F_IN) ? W[k * HID + n] : 0.f;
  unsigned short h = f2bf(v);
  float lf = v - bf2f(h);
  unsigned short lo = f2bf(lf);
  int ks = k >> 5, oct = (k >> 3) & 3, j = k & 7;
  int nf = n >> 4;
  int l = (n & 15) | (oct << 4);
  int addr = ((ks * 16 + nf) * 64 + l) * 8 + j;
  Wh[addr] = (short)h;
  Wl[addr] = (short)lo;
}

// ---- GEMM1 (structural floor ~105us; do not touch): A bf16 single plane,
//      B split hi/lo (2-pass MFMA), BK=64 dbuf LDS (16KB), XOR-swizzle,
//      depth-2 chunk prefetch, x-loads issued after barrier, B prefetch
//      1 ks ahead, fused as1/ad1 epilogue. (256,2) only viable bound.
__global__ __launch_bounds__(256, 2) void gemm1_mfma_kernel(
    const float* __restrict__ x, const short* __restrict__ Wh,
    const short* __restrict__ Wl, __half* __restrict__ h1h,
    const float* __restrict__ att_s, const float* __restrict__ att_d,
    float* __restrict__ as1, float* __restrict__ ad1) {
  __shared__ __align__(16) short Ah[2][2][2048];
  const int tid = threadIdx.x;
  const int lane = tid & 63, wav = tid >> 6;
  const int m0 = blockIdx.x * 64;
  const int m_local = tid >> 2, oct = tid & 3;
  const int gm = m0 + m_local;
  const bool vrow = (gm < N_NODES);
  const long xbase = (long)gm * F_IN;
  const int wu0 = ((m_local >> 4) * 64) + ((m_local & 15) | (oct << 4));
  const int wu = wu0 ^ ((((unsigned)wu0 >> 4) & 3) << 1);

  float atts[4], attd[4];
#pragma unroll
  for (int nf = 0; nf < 4; ++nf) {
    int c = wav * 64 + nf * 16 + (lane & 15);
    atts[nf] = att_s[c];
    attd[nf] = att_d[c];
  }

  f32x4 acc[4][4];
#pragma unroll
  for (int i = 0; i < 4; ++i)
#pragma unroll
    for (int j = 0; j < 4; ++j) acc[i][j] = (f32x4){0.f, 0.f, 0.f, 0.f};

  float xc[16], xn[16];
  {
    int kb = oct * 8;
    if (vrow) {
#pragma unroll
      for (int ki = 0; ki < 2; ++ki)
#pragma unroll
        for (int j = 0; j < 8; ++j) {
          xc[ki * 8 + j] = x[xbase + kb + ki * 32 + j];
          xn[ki * 8 + j] = x[xbase + 64 + kb + ki * 32 + j];
        }
    } else {
#pragma unroll
      for (int j = 0; j < 16; ++j) { xc[j] = 0.f; xn[j] = 0.f; }
    }
  }
  short8 bhc[4], blc[4];
  {
    const short* wb = Wh + ((wav * 4) * 64 + lane) * 8;
    const short* wbl = Wl + ((wav * 4) * 64 + lane) * 8;
#pragma unroll
    for (int nf = 0; nf < 4; ++nf) {
      bhc[nf] = *(const short8*)(wb + nf * 512);
      blc[nf] = *(const short8*)(wbl + nf * 512);
    }
  }

#pragma unroll 2
  for (int c = 0; c < NCH; ++c) {
#pragma unroll
    for (int ki = 0; ki < 2; ++ki) {
      short8 hi8;
#pragma unroll
      for (int j = 0; j < 8; ++j) hi8[j] = (short)f2bf(xc[ki * 8 + j]);
      *(short8*)&Ah[c & 1][ki][wu * 8] = hi8;
    }
    __syncthreads();  // drains only loads issued >=1 chunk ago (~free)
    {
#pragma unroll
      for (int j = 0; j < 16; ++j) xc[j] = xn[j];
      int s = c + 2;
      if (s < NCH - 1) {
        int kb = s * 64 + oct * 8;
        if (vrow) {
#pragma unroll
          for (int ki = 0; ki < 2; ++ki)
#pragma unroll
            for (int j = 0; j < 8; ++j) xn[ki * 8 + j] = x[xbase + kb + ki * 32 + j];
        } else {
#pragma unroll
          for (int j = 0; j < 16; ++j) xn[j] = 0.f;
        }
      } else if (s == NCH - 1) {
        int kb = s * 64 + oct * 8;
#pragma unroll
        for (int ki = 0; ki < 2; ++ki)
#pragma unroll
          for (int j = 0; j < 8; ++j) {
            int k = kb + ki * 32 + j;
            xn[ki * 8 + j] = (vrow && k < F_IN) ? x[xbase + k] : 0.f;
          }
      }
    }
#pragma unroll
    for (int ki = 0; ki < 2; ++ki) {
      const int ksg = c * 2 + ki;
      short8 ah[4];
#pragma unroll
      for (int mf = 0; mf < 4; ++mf) {
        int u = mf * 64 + lane;
        int us = u ^ ((((unsigned)u >> 4) & 3) << 1);
        ah[mf] = *(short8*)&Ah[c & 1][ki][us * 8];
      }
      short8 bhn[4], bln[4];
      if (ksg + 1 < KSTEPS) {
        const short* wb = Wh + (((ksg + 1) * 16 + wav * 4) * 64 + lane) * 8;
        const short* wbl = Wl + (((ksg + 1) * 16 + wav * 4) * 64 + lane) * 8;
#pragma unroll
        for (int nf = 0; nf < 4; ++nf) {
          bhn[nf] = *(const short8*)(wb + nf * 512);
          bln[nf] = *(const short8*)(wbl + nf * 512);
        }
      }
#pragma unroll
      for (int mf = 0; mf < 4; ++mf)
#pragma unroll
        for (int nf = 0; nf < 4; ++nf)
          acc[mf][nf] = __builtin_amdgcn_mfma_f32_16x16x32_bf16(ah[mf], bhc[nf], acc[mf][nf], 0, 0, 0);
#pragma unroll
      for (int mf = 0; mf < 4; ++mf)
#pragma unroll
        for (int nf = 0; nf < 4; ++nf)
          acc[mf][nf] = __builtin_amdgcn_mfma_f32_16x16x32_bf16(ah[mf], blc[nf], acc[mf][nf], 0, 0, 0);
#pragma unroll
      for (int nf = 0; nf < 4; ++nf) {
        bhc[nf] = bhn[nf];
        blc[nf] = bln[nf];
      }
    }
  }

  const int r0 = (lane >> 4) * 4, cn = lane & 15;
#pragma unroll
  for (int mf = 0; mf < 4; ++mf) {
    int rowb = m0 + mf * 16 + r0;
#pragma unroll
    for (int rr = 0; rr < 4; ++rr) {
      int row = rowb + rr;
      bool ok = (row < N_NODES);
      if (ok) {
#pragma unroll
        for (int nf = 0; nf < 4; ++nf)
          h1h[(long)row * HID + wav * 64 + nf * 16 + cn] =
              __float2half_rn(acc[mf][nf][rr]);
      }
      float s0 = acc[mf][0][rr] * atts[0] + acc[mf][1][rr] * atts[1];
      float s1 = acc[mf][2][rr] * atts[2] + acc[mf][3][rr] * atts[3];
      float d0 = acc[mf][0][rr] * attd[0] + acc[mf][1][rr] * attd[1];
      float d1 = acc[mf][2][rr] * attd[2] + acc[mf][3][rr] * attd[3];
#pragma unroll
      for (int o = 1; o < 16; o <<= 1) {
        s0 += __shfl_xor(s0, o, 64);
        s1 += __shfl_xor(s1, o, 64);
        d0 += __shfl_xor(d0, o, 64);
        d1 += __shfl_xor(d1, o, 64);
      }
      if (ok && cn == 0) {
        as1[row * NHEAD + wav * 2]     = s0;
        as1[row * NHEAD + wav * 2 + 1] = s1;
        ad1[row * NHEAD + wav * 2]     = d0;
        ad1[row * NHEAD + wav * 2 + 1] = d1;
      }
    }
  }
}

// ---------------- CSR build ----------------
__global__ void count_kernel(const int* __restrict__ ei, int* __restrict__ deg) {
  int e = blockIdx.x * blockDim.x + threadIdx.x;
  if (e >= EL) return;
  int dst = (e < N_EDGES) ? ei[N_EDGES + e] : (e - N_EDGES);
  atomicAdd(&deg[dst], 1);
}

__global__ __launch_bounds__(1024) void scan_part_kernel(
    const int* __restrict__ deg, int* __restrict__ off, int* __restrict__ btot) {
  __shared__ int warp_sums[16];
  const int tid = threadIdx.x;
  const int lane = tid & 63, wid = tid >> 6;
  int i = blockIdx.x * 1024 + tid;
  int v = (i < N_NODES) ? deg[i] : 0;
  int x = v;
#pragma unroll
  for (int o = 1; o < 64; o <<= 1) {
    int y = __shfl_up(x, o, 64);
    if (lane >= o) x += y;
  }
  if (lane == 63) warp_sums[wid] = x;
  __syncthreads();
  if (wid == 0) {
    int ws = (lane < 16) ? warp_sums[lane] : 0;
#pragma unroll
    for (int o = 1; o < 16; o <<= 1) {
      int y = __shfl_up(ws, o, 64);
      if (lane >= o) ws += y;
    }
    if (lane < 16) warp_sums[lane] = ws;
  }
  __syncthreads();
  int wprefix = (wid > 0) ? warp_sums[wid - 1] : 0;
  if (i < N_NODES) off[i] = wprefix + x - v;
  if (tid == 1023) btot[blockIdx.x] = warp_sums[15];
}

__global__ __launch_bounds__(64) void scan_tops_kernel(
    const int* __restrict__ btot, int* __restrict__ bo) {
  int lane = threadIdx.x;
  int v = (lane < NB_SCAN) ? btot[lane] : 0;
  int x = v;
#pragma unroll
  for (int o = 1; o < 64; o <<= 1) {
    int y = __shfl_up(x, o, 64);
    if (lane >= o) x += y;
  }
  if (lane < NB_SCAN) bo[lane] = x - v;  // exclusive
}

__global__ void scan_add_kernel(int* __restrict__ off, const int* __restrict__ bo) {
  int i = blockIdx.x * blockDim.x + threadIdx.x;
  if (i > N_NODES) return;
  if (i == N_NODES) off[i] = EL;
  else off[i] += bo[i >> 10];
}

// ---- fill CSR (pure; attention numerators computed inline in agg1) ----
__global__ void fill_kernel(const int* __restrict__ ei, const int* __restrict__ off,
                            int* __restrict__ cur, int* __restrict__ csr) {
  int e = blockIdx.x * blockDim.x + threadIdx.x;
  if (e >= EL) return;
  int src, dst;
  if (e < N_EDGES) { src = ei[e]; dst = ei[N_EDGES + e]; }
  else { src = e - N_EDGES; dst = src; }
  int pos = atomicAdd(&cur[dst], 1);
  csr[off[dst] + pos] = src;
}

// ---- layer-1 aggregation (inline no-max softmax) + FUSED layer-2 linear ----
// 8 nodes/block, 32 thr/node, 16B h1 gathers (8 ch/thread), 4-edge unroll.
// W2 in per-thread-row swizzled LDS: W2s[t*81 + c*10 + k]; 81 is odd so
// 81*t mod 32 = 17t mod 32 is bijective across 32 lanes -> ZERO bank
// conflicts (was 8-way: stride-88 hit only 4 banks; 1.85e7 conflict cycles).
__global__ __launch_bounds__(256) void agg1_kernel(
    const __half* __restrict__ h1h, const float* __restrict__ as1,
    const float* __restrict__ ad1, const int* __restrict__ off,
    const int* __restrict__ csr, const float* __restrict__ b1,
    const float* __restrict__ W2, const float* __restrict__ att_s2,
    const float* __restrict__ att_d2, float* __restrict__ h2,
    float* __restrict__ as2, float* __restrict__ ad2) {
  __shared__ float W2s[32 * 81];  // [t][80 vals], stride 81 (odd -> bijective)
  {
    int tid = threadIdx.x;
    for (int i = tid; i < 32 * 80; i += 256)
      W2s[(i / 80) * 81 + (i % 80)] = W2[i];  // (t*8+c)*10+k == t*80 + (c*10+k)
  }
  __syncthreads();
  const int t = threadIdx.x & 31;
  const int n = blockIdx.x * 8 + (threadIdx.x >> 5);
  if (n >= N_NODES) return;
  const int head = t >> 2;  // channels t*8..t*8+7 all inside head t/4
  const float adn = ad1[n * NHEAD + head];
  const int j0 = off[n], j1 = off[n + 1];
  float a[8] = {0.f, 0.f, 0.f, 0.f, 0.f, 0.f, 0.f, 0.f};
  float den = 0.f;
  int j = j0;
  for (; j + 3 < j1; j += 4) {
    int s[4];
    float pw[4];
    float4 v[4];
#pragma unroll
    for (int q = 0; q < 4; ++q) s[q] = csr[j + q];
#pragma unroll
    for (int q = 0; q < 4; ++q) {
      float e = as1[s[q] * NHEAD + head] + adn;
      e = (e >= 0.f) ? e : 0.2f * e;
      pw[q] = __expf(e);
      v[q] = *(const float4*)&h1h[s[q] * HID + t * 8];
    }
#pragma unroll
    for (int q = 0; q < 4; ++q) {
      const __half2* hp = (const __half2*)&v[q];
      den += pw[q];
#pragma unroll
      for (int c2 = 0; c2 < 4; ++c2) {
        float2 f = __half22float2(hp[c2]);
        a[2 * c2]     += pw[q] * f.x;
        a[2 * c2 + 1] += pw[q] * f.y;
      }
    }
  }
  for (; j < j1; ++j) {
    int s0 = csr[j];
    float e = as1[s0 * NHEAD + head] + adn;
    e = (e >= 0.f) ? e : 0.2f * e;
    float p0 = __expf(e);
    float4 v0 = *(const float4*)&h1h[s0 * HID + t * 8];
    const __half2* hp = (const __half2*)&v0;
    den += p0;
#pragma unroll
    for (int c2 = 0; c2 < 4; ++c2) {
      float2 f = __half22float2(hp[c2]);
      a[2 * c2]     += p0 * f.x;
      a[2 * c2 + 1] += p0 * f.y;
    }
  }
  float rden = 1.f / (den + 1e-16f);
  float4 bv0 = *(const float4*)&b1[t * 8];
  float4 bv1 = *(const float4*)&b1[t * 8 + 4];
  float vv[8];
  vv[0] = a[0] * rden + bv0.x;
  vv[1] = a[1] * rden + bv0.y;
  vv[2] = a[2] * rden + bv0.z;
  vv[3] = a[3] * rden + bv0.w;
  vv[4] = a[4] * rden + bv1.x;
  vv[5] = a[5] * rden + bv1.y;
  vv[6] = a[6] * rden + bv1.z;
  vv[7] = a[7] * rden + bv1.w;
#pragma unroll
  for (int c = 0; c < 8; ++c) vv[c] = (vv[c] > 0.f) ? vv[c] : (__expf(vv[c]) - 1.f);
  // fused layer-2 linear: h2[n][k] = sum_c o1[n][c]*W2[c][k], 32-lane reduce
  const float* w2t = &W2s[t * 81];
  float hk[10];
#pragma unroll
  for (int k = 0; k < 10; ++k) {
    float pk = 0.f;
#pragma unroll
    for (int c = 0; c < 8; ++c) pk += vv[c] * w2t[c * 10 + k];
#pragma unroll
    for (int o = 16; o >= 1; o >>= 1) pk += __shfl_xor(pk, o, 64);
    hk[k] = pk;
  }
  if (t == 0) {
    float s = 0.f, d = 0.f;
#pragma unroll
    for (int k = 0; k < 10; ++k) {
      h2[n * 10 + k] = hk[k];
      s += hk[k] * att_s2[k];
      d += hk[k] * att_d2[k];
    }
    as2[n] = s;
    ad2[n] = d;
  }
}

// ---- layer-2 aggregation: 16-lane sub-groups, 16 nodes/block ----
__global__ __launch_bounds__(256) void agg2_kernel(
    const float* __restrict__ h2, const float* __restrict__ as2,
    const float* __restrict__ ad2, const int* __restrict__ off,
    const int* __restrict__ csr, const float* __restrict__ b2,
    float* __restrict__ out) {
  int g = threadIdx.x >> 4, l = threadIdx.x & 15;
  int n = blockIdx.x * 16 + g;
  if (n >= N_NODES) return;
  float adn = ad2[n];
  int j0 = off[n], j1 = off[n + 1];
  float acc = 0.f, den = 0.f;
  int j = j0;
  for (; j + 1 < j1; j += 2) {
    int s0 = csr[j], s1 = csr[j + 1];
    float e0 = as2[s0] + adn, e1 = as2[s1] + adn;
    e0 = (e0 >= 0.f) ? e0 : 0.2f * e0;
    e1 = (e1 >= 0.f) ? e1 : 0.2f * e1;
    float p0 = __expf(e0), p1v = __expf(e1);
    den += p0 + p1v;
    if (l < 10) acc += p0 * h2[s0 * 10 + l] + p1v * h2[s1 * 10 + l];
  }
  if (j < j1) {
    int s0 = csr[j];
    float e0 = as2[s0] + adn;
    e0 = (e0 >= 0.f) ? e0 : 0.2f * e0;
    float p0 = __expf(e0);
    den += p0;
    if (l < 10) acc += p0 * h2[s0 * 10 + l];
  }
  if (l < 10) out[n * 10 + l] = acc / (den + 1e-16f) + b2[l];
}

extern "C" void kernel_launch(void* const* d_in, const int* in_sizes, int n_in,
                              void* d_out, int out_size, void* d_ws, size_t ws_size,
                              hipStream_t stream) {
  const float* x    = (const float*)d_in[0];
  const int*   ei   = (const int*)d_in[1];
  const float* W1   = (const float*)d_in[2];
  const float* as1w = (const float*)d_in[3];
  const float* ad1w = (const float*)d_in[4];
  const float* b1   = (const float*)d_in[5];
  const float* W2   = (const float*)d_in[6];
  const float* as2w = (const float*)d_in[7];
  const float* ad2w = (const float*)d_in[8];
  const float* b2   = (const float*)d_in[9];
  float* out = (float*)d_out;

  char* p = (char*)d_ws;
  __half* h1h = (__half*)p; p += (size_t)N_NODES * HID * 2;
  float* a_s1 = (float*)p; p += (size_t)N_NODES * NHEAD * 4;
  float* a_d1 = (float*)p; p += (size_t)N_NODES * NHEAD * 4;
  float* h2   = (float*)p; p += (size_t)N_NODES * 10 * 4;
  float* a_s2 = (float*)p; p += (size_t)N_NODES * 4;
  float* a_d2 = (float*)p; p += (size_t)N_NODES * 4;
  short* Wh   = (short*)p; p += (size_t)KSTEPS * 16 * 64 * 8 * 2;
  short* Wl   = (short*)p; p += (size_t)KSTEPS * 16 * 64 * 8 * 2;
  int* deg    = (int*)p;   p += (size_t)N_NODES * 4;
  int* cur    = (int*)p;   p += (size_t)N_NODES * 4;
  int* off    = (int*)p;   p += (size_t)(N_NODES + 1) * 4;
  int* csr    = (int*)p;   p += (size_t)EL * 4;
  int* btot   = (int*)p;   p += 64 * 4;
  int* bo     = (int*)p;   p += 64 * 4;

  prep_kernel<<<768, 256, 0, stream>>>(W1, Wh, Wl, deg, cur);
  gemm1_mfma_kernel<<<(N_NODES + 63) / 64, 256, 0, stream>>>(
      x, Wh, Wl, h1h, as1w, ad1w, a_s1, a_d1);
  count_kernel<<<(EL + 255) / 256, 256, 0, stream>>>(ei, deg);
  scan_part_kernel<<<NB_SCAN, 1024, 0, stream>>>(deg, off, btot);
  scan_tops_kernel<<<1, 64, 0, stream>>>(btot, bo);
  scan_add_kernel<<<(N_NODES + 256) / 256, 256, 0, stream>>>(off, bo);
  fill_kernel<<<(EL + 255) / 256, 256, 0, stream>>>(ei, off, cur, csr);
  agg1_kernel<<<(N_NODES + 7) / 8, 256, 0, stream>>>(
      h1h, a_s1, a_d1, off, csr, b1, W2, as2w, ad2w, h2, a_s2, a_d2);
  agg2_kernel<<<(N_NODES + 15) / 16, 256, 0, stream>>>(h2, a_s2, a_d2, off, csr, b2, out);
}